// Round 5
// baseline (292.319 us; speedup 1.0000x reference)
//
#include <hip/hip_runtime.h>
#include <hip/hip_bf16.h>
#include <math.h>

// Problem constants
#define DIM   1024
#define NHEAD 16
#define SLEN  2048
#define BATCH 2
#define NROWS (BATCH*SLEN)   // 4096
#define QKV_N 3072

typedef __attribute__((ext_vector_type(8))) short short8v;
typedef __attribute__((ext_vector_type(4))) short short4v;
typedef __attribute__((ext_vector_type(4))) float f32x4;
typedef __attribute__((ext_vector_type(4))) unsigned int u32x4;

// RNE float->bf16 bit tricks (valid for finite, non-overflowing inputs —
// identical result to __float2bfloat16 / jnp astype for our value ranges)
__device__ __forceinline__ unsigned short rne16(float f) {
  unsigned u = __float_as_uint(f);
  u += 0x7FFFu + ((u >> 16) & 1u);
  return (unsigned short)(u >> 16);
}
__device__ __forceinline__ float rnef(float f) {
  unsigned u = __float_as_uint(f);
  u += 0x7FFFu + ((u >> 16) & 1u);
  return __uint_as_float(u & 0xFFFF0000u);
}
// pack two floats as bf16 pair (RNE), low = a, high = b.
// v_cvt_pk_bf16_f32 is RNE on gfx950 -> bit-identical to the bit-trick pk2,
// 1 VALU op instead of 5 (T12 recipe).
__device__ __forceinline__ unsigned pk2(float a, float b) {
  unsigned r;
  asm("v_cvt_pk_bf16_f32 %0, %1, %2" : "=v"(r) : "v"(a), "v"(b));
  return r;
}

// async global->LDS, 16 bytes per lane; LDS dest = wave-uniform base + lane*16
__device__ __forceinline__ void gld16(const unsigned short* g, unsigned short* l) {
  __builtin_amdgcn_global_load_lds(
      (const __attribute__((address_space(1))) unsigned int*)g,
      (__attribute__((address_space(3))) unsigned int*)l, 16, 0, 0);
}

// ================= k_prep: all independent input transforms =================
// blocks [0,12288)        ternary(w_qkv) -> bf16 Wb
// blocks [12288,16384)    ternary(protos) -> fp32 PT
// blocks [16384,20480)    xsplit (x -> Xhi,Xlo)
// blocks [20480,20736)    rope tables
// blocks [20736,20768)    feature split FS/FD
__global__ void __launch_bounds__(256) k_prep(
    const float* __restrict__ w_qkv, const float* __restrict__ protos,
    const float* __restrict__ x, const float* __restrict__ F,
    unsigned short* __restrict__ Wb, float* __restrict__ PT,
    unsigned short* __restrict__ Xhi, unsigned short* __restrict__ Xlo,
    float* __restrict__ cosT, float* __restrict__ sinT,
    float* __restrict__ FS, float* __restrict__ FD) {
  const int blk = blockIdx.x, tid = threadIdx.x;
  if (blk < 12288) {                       // ternary -> bf16
    int idx = blk * 256 + tid;
    float wb = rnef(w_qkv[idx]);
    float a = fabsf(wb);
    #pragma unroll
    for (int off = 32; off >= 1; off >>= 1) a += __shfl_xor(a, off);
    float scale = fmaxf(rnef(a * (1.0f / 64.0f)), 1e-8f);
    float q = fminf(1.0f, fmaxf(-1.0f, rintf(rnef(wb / scale))));
    float deq = rnef(q * scale);
    float d = rnef(deq - wb);
    Wb[idx] = rne16(wb + d);
  } else if (blk < 16384) {                // ternary -> fp32 (prototypes)
    int idx = (blk - 12288) * 256 + tid;
    float wb = rnef(protos[idx]);
    float a = fabsf(wb);
    #pragma unroll
    for (int off = 32; off >= 1; off >>= 1) a += __shfl_xor(a, off);
    float scale = fmaxf(rnef(a * (1.0f / 64.0f)), 1e-8f);
    float q = fminf(1.0f, fmaxf(-1.0f, rintf(rnef(wb / scale))));
    float deq = rnef(q * scale);
    float d = rnef(deq - wb);
    PT[idx] = rnef(wb + d);
  } else if (blk < 20480) {                // xsplit
    int idx = (blk - 16384) * 256 + tid;
    float4 v = *(const float4*)(x + (size_t)idx * 4);
    short4v hi, lo;
    float h0 = rnef(v.x); hi[0] = (short)rne16(v.x); lo[0] = (short)rne16(v.x - h0);
    float h1 = rnef(v.y); hi[1] = (short)rne16(v.y); lo[1] = (short)rne16(v.y - h1);
    float h2 = rnef(v.z); hi[2] = (short)rne16(v.z); lo[2] = (short)rne16(v.z - h2);
    float h3 = rnef(v.w); hi[3] = (short)rne16(v.w); lo[3] = (short)rne16(v.w - h3);
    *(short4v*)(Xhi + (size_t)idx * 4) = hi;
    *(short4v*)(Xlo + (size_t)idx * 4) = lo;
  } else if (blk < 20736) {                // rope tables
    int idx = (blk - 20480) * 256 + tid;   // 65536
    int s = idx >> 5, j = idx & 31;
    double inv  = 1.0 / pow(10000.0, (double)(2 * j) / 64.0);
    double ramp = ((double)(2 * j) / 64.0 - 0.25) / 0.75;
    ramp = ramp < 0.0 ? 0.0 : (ramp > 1.0 ? 1.0 : ramp);
    inv /= (ramp * 3.0 + 1.0);
    float freq = (float)s * (float)inv;
    cosT[idx] = (float)cos((double)freq);
    sinT[idx] = (float)sin((double)freq);
  } else {                                 // fsplit
    int idx = (blk - 20736) * 256 + tid;   // 8192
    int f = idx >> 9, hd = idx & 511;
    int h = hd >> 5, d = hd & 31;
    float a = F[f * 1024 + h * 64 + d];
    float b = F[f * 1024 + h * 64 + 32 + d];
    FS[idx] = a + b;
    FD[idx] = b - a;
  }
}

// ===== 256x192 shared-B 4-phase bf16 MFMA GEMM =====
// C[4096][3072] = (Xhi+Xlo)·Wb^T. grid 16x16 = 256 blocks (all CUs busy).
// Per iteration (kc = i*64): B(kc) staged once (dbuf), read once to regs,
// reused by 4 phases: (qm0,hi),(qm1,hi),(qm0,lo),(qm1,lo), 24 MFMA each.
// A single-buffered with half-granularity overwrite (half freed 1 phase
// before restage; every stage->read pair has >=3 phases landing margin).
// LDS 112 KiB: AHI 32K | ALO 32K | B 2x24K, st_16x32 XOR swizzle.
// Counted vmcnt at phase ends: 4/4/7/7 steady-state, never 0 until drain.
#define FEN() asm volatile("" ::: "memory")
#define SB()  do { FEN(); __builtin_amdgcn_s_barrier(); FEN(); } while (0)
#define WL()  do { asm volatile("s_waitcnt lgkmcnt(0)" ::: "memory"); \
                   __builtin_amdgcn_sched_barrier(0); } while (0)
#define WVN(n) asm volatile("s_waitcnt vmcnt(" #n ")" ::: "memory")

__global__ void __launch_bounds__(512, 2) k_gemm4(
    const unsigned short* __restrict__ Xhi, const unsigned short* __restrict__ Xlo,
    const unsigned short* __restrict__ Wb, float* __restrict__ C) {
  __shared__ unsigned char lds[114688];
  const int t = threadIdx.x;
  const int lane = t & 63;
  const int qL = lane & 15, quad = lane >> 4;
  const int wid = t >> 6;
  const int wm = wid >> 2, wn = wid & 3;   // 2M x 4N waves; per-wave 128x48
  // XCD-aware swizzle: 256 % 8 == 0 -> bijective
  const int bid = blockIdx.x;
  const int swz = (bid & 7) * 32 + (bid >> 3);
  const int by = swz >> 4, bx = swz & 15;
  const int bm = by * 256, bn = bx * 192;
  // swizzled ds_read inner offset (st_16x32 within 1024B subtile)
  const int inner = qL * 64 + ((quad * 16) ^ ((qL & 8) << 2));
  // staging decode: linear dest L -> logical (row, col) via involution P
  int rj[3], cj[3];
  #pragma unroll
  for (int j = 0; j < 3; ++j) {
    int L = j * 8192 + t * 16;
    int Lp = L ^ (((L >> 9) & 1) << 5);
    int st = Lp >> 10;
    rj[j] = (st >> 1) * 16 + ((Lp >> 6) & 15);
    cj[j] = (st & 1) * 32 + ((Lp & 63) >> 1);
  }
  unsigned char* AHI = lds;                 // 2 halves x 16K
  unsigned char* ALO = lds + 32768;         // 2 halves x 16K
  unsigned char* BB  = lds + 65536;         // 2 bufs x 24K

  // stage A half-tile (128 rows interleaved as wm-blocks) of panel at kc
  auto STA = [&](const unsigned short* __restrict__ pan, unsigned char* reg,
                 int kc, int h) {
    unsigned char* lb = reg + h * 16384 + (t >> 6) * 1024;
    #pragma unroll
    for (int j = 0; j < 2; ++j) {
      int rr = bm + ((rj[j] >> 6) * 128) + h * 64 + (rj[j] & 63);
      gld16(pan + (size_t)rr * 1024 + kc + cj[j], (unsigned short*)(lb + j * 8192));
    }
  };
  // stage whole B tile (192 rows) of kc into buf
  auto STB = [&](int kc, int buf) {
    unsigned char* lb = BB + buf * 24576 + (t >> 6) * 1024;
    #pragma unroll
    for (int j = 0; j < 3; ++j)
      gld16(Wb + (size_t)(bn + rj[j]) * 1024 + kc + cj[j],
            (unsigned short*)(lb + j * 8192));
  };

  short8v aF[4][2], bF[3][2];
  f32x4 acc[2][4][3];
  const f32x4 zz = {0.f, 0.f, 0.f, 0.f};
  #pragma unroll
  for (int q_ = 0; q_ < 2; ++q_)
    #pragma unroll
    for (int m_ = 0; m_ < 4; ++m_)
      #pragma unroll
      for (int n_ = 0; n_ < 3; ++n_) acc[q_][m_][n_] = zz;

  auto RA = [&](unsigned char* reg, int qm_) {
    #pragma unroll
    for (int mi = 0; mi < 4; ++mi)
      #pragma unroll
      for (int ks = 0; ks < 2; ++ks)
        aF[mi][ks] = *(const short8v*)(reg + qm_ * 16384 +
                                       ((((wm * 4 + mi) << 1) + ks) << 10) + inner);
  };
  auto RB = [&](int buf) {
    #pragma unroll
    for (int ni = 0; ni < 3; ++ni)
      #pragma unroll
      for (int ks = 0; ks < 2; ++ks)
        bF[ni][ks] = *(const short8v*)(BB + buf * 24576 +
                                       ((((wn * 3 + ni) << 1) + ks) << 10) + inner);
  };
  auto MM = [&](int qm_) {
    __builtin_amdgcn_s_setprio(1);
    #pragma unroll
    for (int ks = 0; ks < 2; ++ks)       // ks outer: dependent pairs 12 apart
      #pragma unroll
      for (int mi = 0; mi < 4; ++mi)
        #pragma unroll
        for (int ni = 0; ni < 3; ++ni)
          acc[qm_][mi][ni] = __builtin_amdgcn_mfma_f32_16x16x32_bf16(
              aF[mi][ks], bF[ni][ks], acc[qm_][mi][ni], 0, 0, 0);
    __builtin_amdgcn_s_setprio(0);
  };

  // prologue: B(0) + Ahi halves + Alo-h0 (9 units); leave newest 4 in flight
  STB(0, 0); STA(Xhi, AHI, 0, 0); STA(Xhi, AHI, 0, 1); STA(Xlo, ALO, 0, 0);
  WVN(4);
  SB();

  #pragma unroll 1
  for (int i = 0; i < 16; ++i) {
    const int kc = i * 64, kn = kc + 64;
    const bool nl = (i < 15);
    const int cb = i & 1, nb = cb ^ 1;
    // ph1: (qm0, hi) — read B once for the whole iteration
    RA(AHI, 0); RB(cb); STA(Xlo, ALO, kc, 1);
    SB(); WL(); MM(0);
    WVN(4);                                   // Ahi-h1(i) landed
    SB();
    // ph2: (qm1, hi)
    RA(AHI, 1);
    if (nl) { STB(kn, nb); STA(Xhi, AHI, kn, 0); }
    SB(); WL(); MM(1);
    if (nl) { WVN(7); } else { WVN(2); }      // Alo-h0(i) landed
    SB();
    // ph3: (qm0, lo)
    RA(ALO, 0);
    if (nl) STA(Xhi, AHI, kn, 1);
    SB(); WL(); MM(0);
    if (nl) { WVN(7); } else { WVN(0); }      // Alo-h1(i) landed
    SB();
    // ph4: (qm1, lo)
    RA(ALO, 1);
    if (nl) STA(Xlo, ALO, kn, 0);
    SB(); WL(); MM(1);
    if (nl) WVN(4);                           // B(i+1), Ahi-h0(i+1) landed
    SB();
  }

  // epilogue: C write (row from A via (quad,reg); col from B via qL)
  #pragma unroll
  for (int qm_ = 0; qm_ < 2; ++qm_)
    #pragma unroll
    for (int mi = 0; mi < 4; ++mi) {
      const int row0 = bm + wm * 128 + qm_ * 64 + mi * 16 + quad * 4;
      #pragma unroll
      for (int ni = 0; ni < 3; ++ni) {
        const int col = bn + wn * 48 + ni * 16 + qL;
        #pragma unroll
        for (int r = 0; r < 4; ++r)
          C[(size_t)(row0 + r) * QKV_N + col] = acc[qm_][mi][ni][r];
      }
    }
}

// ================= k_mid: normrope + vtrans + protproj ======================
// blocks [0,32768)        rmsnorm+rope+gain -> QB16/KB16
// blocks [32768,34816)    V transpose -> VT16
// blocks [34816,35072)    prototype projection -> A1T/A2T
__device__ __forceinline__ float dot4(float4 a, float4 b) {
  return fmaf(a.x, b.x, fmaf(a.y, b.y, fmaf(a.z, b.z, a.w * b.w)));
}
__global__ void __launch_bounds__(256) k_mid(const float* __restrict__ QKV,
    const float* __restrict__ cosT, const float* __restrict__ sinT,
    const float* __restrict__ q_gain,
    unsigned short* __restrict__ QB16, unsigned short* __restrict__ KB16,
    unsigned short* __restrict__ VT16,
    const float* __restrict__ PT, const float* __restrict__ F,
    const float* __restrict__ thp, const float* __restrict__ alp,
    const float* __restrict__ bep,
    float* __restrict__ A1T, float* __restrict__ A2T) {
  __shared__ short Vt[64][34];
  const int blk = blockIdx.x, t = threadIdx.x;
  if (blk < 32768) {                       // normrope
    int gid = blk * 256 + t;
    int lane = gid & 63;
    int w = gid >> 6;
    int r = w >> 5;
    int u = w & 31;
    int isk = u >> 4, h = u & 15;
    float x = QKV[(size_t)r * 3072 + isk * 1024 + h * 64 + lane];
    float ss = x * x;
    #pragma unroll
    for (int off = 32; off >= 1; off >>= 1) ss += __shfl_xor(ss, off);
    float xn = x * rsqrtf(ss * (1.0f / 64.0f) + 1e-5f);
    int s = r & (SLEN - 1);
    int b = r >> 11;
    int j = lane & 31;
    float c = cosT[s * 32 + j], sn = sinT[s * 32 + j];
    float other = __shfl_xor(xn, 32);
    float o = (lane < 32) ? fmaf(xn, c, other * sn) : fmaf(xn, c, -other * sn);
    int hh = h + 16 * (lane >> 5);
    int dd = lane & 31;
    size_t addr = (((size_t)(b * 32 + hh) * SLEN) + s) * 32 + dd;
    if (!isk) {
      const float FOLD = 0.17677669529663687f * 1.4426950408889634f;
      QB16[addr] = rne16(o * q_gain[h] * FOLD);
    } else {
      KB16[addr] = rne16(o);
    }
  } else if (blk < 34816) {                // vtrans
    int i = blk - 32768;
    const int s0 = (i & 31) * 64, hh = (i >> 5) & 31, b = i >> 10;
    const int vcb = 2048 + (hh & 15) * 64 + (hh >> 4) * 32;
    {
      int row = t >> 2, dpart = (t & 3) * 8;
      const float* p = QKV + (size_t)(b * SLEN + s0 + row) * 3072 + vcb + dpart;
      float4 a = *(const float4*)p;
      float4 bq = *(const float4*)(p + 4);
      Vt[row][dpart + 0] = (short)rne16(a.x);  Vt[row][dpart + 1] = (short)rne16(a.y);
      Vt[row][dpart + 2] = (short)rne16(a.z);  Vt[row][dpart + 3] = (short)rne16(a.w);
      Vt[row][dpart + 4] = (short)rne16(bq.x); Vt[row][dpart + 5] = (short)rne16(bq.y);
      Vt[row][dpart + 6] = (short)rne16(bq.z); Vt[row][dpart + 7] = (short)rne16(bq.w);
    }
    __syncthreads();
    {
      int d = t >> 3, spart = (t & 7) * 8;
      short8v v;
      #pragma unroll
      for (int k = 0; k < 8; ++k) v[k] = Vt[spart + k][d];
      *(short8v*)(VT16 + (((size_t)(b * 32 + hh) * 32) + d) * SLEN + s0 + spart) = v;
    }
  } else {                                 // protproj (coalesced)
    const int w = t >> 6, lane = t & 63;
    const int o = (blk - 34816) * 4 + w;
    const float* pr = PT + (size_t)o * 1024;
    float4 p0 = *(const float4*)(pr + lane * 4);
    float4 p1 = *(const float4*)(pr + 256 + lane * 4);
    float4 p2 = *(const float4*)(pr + 512 + lane * 4);
    float4 p3 = *(const float4*)(pr + 768 + lane * 4);
    float acc[16];
    #pragma unroll
    for (int f = 0; f < 16; ++f) {
      const float* fr = F + (size_t)f * 1024;
      float4 f0 = *(const float4*)(fr + lane * 4);
      float4 f1 = *(const float4*)(fr + 256 + lane * 4);
      float4 f2 = *(const float4*)(fr + 512 + lane * 4);
      float4 f3 = *(const float4*)(fr + 768 + lane * 4);
      acc[f] = dot4(p0, f0) + dot4(p1, f1) + dot4(p2, f2) + dot4(p3, f3);
    }
    #pragma unroll
    for (int f = 0; f < 16; ++f) {
      #pragma unroll
      for (int off = 32; off >= 1; off >>= 1) acc[f] += __shfl_xor(acc[f], off);
    }
    if (lane == 0) {
      float th = fabsf(*thp), al = fabsf(*alp), be = fabsf(*bep);
      #pragma unroll
      for (int f = 0; f < 16; ++f) {
        float pf = acc[f];
        float ps = 1.0f / (1.0f + expf(-5.0f * pf));
        float pa = pf * ps;
        A1T[f * 1024 + o] = th * pa - al * (1.0f - ps);
        A2T[f * 1024 + o] = -be * pa;
      }
    }
  }
}

// ====== MFMA flash attention: split-KV, zero-shuffle P (no LDS round-trip) ==
// 4096 blocks x 256 thr; block fid: combo = fid&63 (XCD-local K/V), qb =
// 63-(fid>>6) (heavy first -> LPT, deep queue). Wave w handles chunks
// c = w, w+4, ...; diagonal tail chunk goes to wave qb&3. Softmax is max-free
// (exp2 direct, scale folded into Q) -> partials combine by pure summation.
//
// Zero-shuffle P: QK^T C-layout gives lane (qL,quad) P[k=4*quad+r][q=qL] for
// both key tiles. PV's B-layout wants lane (qL,quad) to hold 8 consecutive
// k-slots. The PV contraction is key-order invariant, so we DEFINE the k-slot
// order s = 8*quad + 4*tile + r: each lane's 8 B-operand values are exactly
// its own 8 C-layout outputs -> P fragment assembled in-register, no LDS, no
// cross-lane ops. V is gathered in the same permuted order (two 8B loads per
// 16B fragment: orig keys 4Q..4Q+3 and 16+4Q..19+4Q). Tail masks unchanged
// (predicates are per (tile,quad,r), independent of slot order).
__global__ void __launch_bounds__(256, 7) k_attn(
    const unsigned short* __restrict__ QB16,
    const unsigned short* __restrict__ KB16,
    const unsigned short* __restrict__ VT16,
    float* __restrict__ OH) {
  __shared__ float Comb[3][64][18];       // 13,824 B (waves 1..3 publish)
  const int wid = threadIdx.x >> 6;
  const int fid = blockIdx.x;             // 4096 blocks, one (combo,qb) each
  const int combo = fid & 63;
  const int qb = 63 - (fid >> 6);         // big first
  const int b = combo >> 5, hh = combo & 31;
  const int lane = threadIdx.x & 63;
  const int qL = lane & 15, quad = lane >> 4;
  const int q0 = qb * 32;

  const unsigned short* QB = QB16 + (size_t)(b * 32 + hh) * SLEN * 32;
  const unsigned short* KB = KB16 + (size_t)(b * 32 + hh) * SLEN * 32;
  const unsigned short* VT = VT16 + (size_t)(b * 32 + hh) * 32 * SLEN;

  const short8v qf0 = *(const short8v*)(QB + (size_t)(q0 + qL) * 32 + quad * 8);
  const short8v qf1 = *(const short8v*)(QB + (size_t)(q0 + 16 + qL) * 32 + quad * 8);
  const f32x4 zz = {0.f, 0.f, 0.f, 0.f};
  f32x4 a00 = zz, a01 = zz, a10 = zz, a11 = zz;
  float l0 = 0.f, l1 = 0.f;

  const unsigned short* kp0 = KB + (size_t)qL * 32 + quad * 8;
  const unsigned short* vp0 = VT + (size_t)qL * 2048 + quad * 4;

  for (int c = wid; c < qb; c += 4) {    // this wave's full (unmasked) chunks
    const unsigned short* kp = kp0 + (size_t)c * 1024;
    const unsigned short* vp = vp0 + (size_t)c * 32;
    short8v kf0 = *(const short8v*)kp;
    short8v kf1 = *(const short8v*)(kp + 512);
    short4v va0 = *(const short4v*)vp;                  // orig keys 4Q..4Q+3
    short4v vb0 = *(const short4v*)(vp + 16);           // orig keys 16+4Q..
    short4v va1 = *(const short4v*)(vp + 32768);
    short4v vb1 = *(const short4v*)(vp + 32768 + 16);
    short8v vf0 = __builtin_shufflevector(va0, vb0, 0, 1, 2, 3, 4, 5, 6, 7);
    short8v vf1 = __builtin_shufflevector(va1, vb1, 0, 1, 2, 3, 4, 5, 6, 7);
    f32x4 s00 = __builtin_amdgcn_mfma_f32_16x16x32_bf16(kf0, qf0, zz, 0, 0, 0);
    f32x4 s01 = __builtin_amdgcn_mfma_f32_16x16x32_bf16(kf1, qf0, zz, 0, 0, 0);
    f32x4 s10 = __builtin_amdgcn_mfma_f32_16x16x32_bf16(kf0, qf1, zz, 0, 0, 0);
    f32x4 s11 = __builtin_amdgcn_mfma_f32_16x16x32_bf16(kf1, qf1, zz, 0, 0, 0);
    float p00[4], p01[4], p10[4], p11[4];
    #pragma unroll
    for (int r = 0; r < 4; ++r) {
      p00[r] = __builtin_amdgcn_exp2f(s00[r]);
      p01[r] = __builtin_amdgcn_exp2f(s01[r]);
      p10[r] = __builtin_amdgcn_exp2f(s10[r]);
      p11[r] = __builtin_amdgcn_exp2f(s11[r]);
    }
    l0 += (p00[0] + p00[1] + p00[2] + p00[3]) + (p01[0] + p01[1] + p01[2] + p01[3]);
    l1 += (p10[0] + p10[1] + p10[2] + p10[3]) + (p11[0] + p11[1] + p11[2] + p11[3]);
    u32x4 up0 = {pk2(p00[0], p00[1]), pk2(p00[2], p00[3]),
                 pk2(p01[0], p01[1]), pk2(p01[2], p01[3])};
    u32x4 up1 = {pk2(p10[0], p10[1]), pk2(p10[2], p10[3]),
                 pk2(p11[0], p11[1]), pk2(p11[2], p11[3])};
    short8v pf0 = __builtin_bit_cast(short8v, up0);
    short8v pf1 = __builtin_bit_cast(short8v, up1);
    a00 = __builtin_amdgcn_mfma_f32_16x16x32_bf16(vf0, pf0, a00, 0, 0, 0);
    a01 = __builtin_amdgcn_mfma_f32_16x16x32_bf16(vf1, pf0, a01, 0, 0, 0);
    a10 = __builtin_amdgcn_mfma_f32_16x16x32_bf16(vf0, pf1, a10, 0, 0, 0);
    a11 = __builtin_amdgcn_mfma_f32_16x16x32_bf16(vf1, pf1, a11, 0, 0, 0);
  }
  if ((qb & 3) == wid) {                  // tail chunk (diagonal masks)
    const unsigned short* kp = kp0 + (size_t)qb * 1024;
    const unsigned short* vp = vp0 + (size_t)qb * 32;
    short8v kf0 = *(const short8v*)kp;
    short8v kf1 = *(const short8v*)(kp + 512);
    short4v va0 = *(const short4v*)vp;
    short4v vb0 = *(const short4v*)(vp + 16);
    short4v va1 = *(const short4v*)(vp + 32768);
    short4v vb1 = *(const short4v*)(vp + 32768 + 16);
    short8v vf0 = __builtin_shufflevector(va0, vb0, 0, 1, 2, 3, 4, 5, 6, 7);
    short8v vf1 = __builtin_shufflevector(va1, vb1, 0, 1, 2, 3, 4, 5, 6, 7);
    f32x4 s00 = __builtin_amdgcn_mfma_f32_16x16x32_bf16(kf0, qf0, zz, 0, 0, 0);
    f32x4 s10 = __builtin_amdgcn_mfma_f32_16x16x32_bf16(kf0, qf1, zz, 0, 0, 0);
    f32x4 s11 = __builtin_amdgcn_mfma_f32_16x16x32_bf16(kf1, qf1, zz, 0, 0, 0);
    float p00[4], p10[4], p11[4];
    #pragma unroll
    for (int r = 0; r < 4; ++r) {
      bool v = (4 * quad + r) <= qL;      // same predicate for s00 and s11
      p00[r] = v ? __builtin_amdgcn_exp2f(s00[r]) : 0.f;
      p10[r] = __builtin_amdgcn_exp2f(s10[r]);   // always valid
      p11[r] = v ? __builtin_amdgcn_exp2f(s11[r]) : 0.f;
    }
    l0 += (p00[0] + p00[1] + p00[2] + p00[3]);
    l1 += (p10[0] + p10[1] + p10[2] + p10[3]) + (p11[0] + p11[1] + p11[2] + p11[3]);
    u32x4 up0 = {pk2(p00[0], p00[1]), pk2(p00[2], p00[3]), 0u, 0u};
    u32x4 up1 = {pk2(p10[0], p10[1]), pk2(p10[2], p10[3]),
                 pk2(p11[0], p11[1]), pk2(p11[2], p11[3])};
    short8v pf0 = __builtin_bit_cast(short8v, up0);
    short8v pf1 = __builtin_bit_cast(short8v, up1);
    a00 = __builtin_amdgcn_mfma_f32_16x16x32_bf16(vf0, pf0, a00, 0, 0, 0);
    a01 = __builtin_amdgcn_mfma_f32_16x16x32_bf16(vf1, pf0, a01, 0, 0, 0);
    a10 = __builtin_amdgcn_mfma_f32_16x16x32_bf16(vf0, pf1, a10, 0, 0, 0);
    a11 = __builtin_amdgcn_mfma_f32_16x16x32_bf16(vf1, pf1, a11, 0, 0, 0);
  }
  // in-wave l reduction (across quads)
  l0 += __shfl_xor(l0, 16); l0 += __shfl_xor(l0, 32);
  l1 += __shfl_xor(l1, 16); l1 += __shfl_xor(l1, 32);

  // cross-wave combine: waves 1..3 publish unnormalized partials; wave 0 sums
  if (wid > 0) {
    float* cb = &Comb[wid - 1][lane][0];
    #pragma unroll
    for (int r = 0; r < 4; ++r) {
      cb[r]      = a00[r];
      cb[4 + r]  = a01[r];
      cb[8 + r]  = a10[r];
      cb[12 + r] = a11[r];
    }
    cb[16] = l0; cb[17] = l1;
  }
  __syncthreads();
  if (wid == 0) {
    #pragma unroll
    for (int w = 0; w < 3; ++w) {
      const float* cb = &Comb[w][lane][0];
      #pragma unroll
      for (int r = 0; r < 4; ++r) {
        a00[r] += cb[r];
        a01[r] += cb[4 + r];
        a10[r] += cb[8 + r];
        a11[r] += cb[12 + r];
      }
      l0 += cb[16]; l1 += cb[17];
    }
    const float inv0 = 1.0f / l0, inv1 = 1.0f / l1;
    float* ob0 = OH + (((size_t)(b * SLEN + q0 + qL) * 32) + hh) * 32 + (quad << 2);
    float* ob1 = OH + (((size_t)(b * SLEN + q0 + 16 + qL) * 32) + hh) * 32 + (quad << 2);
    *(float4*)ob0        = (float4){a00[0] * inv0, a00[1] * inv0, a00[2] * inv0, a00[3] * inv0};
    *(float4*)(ob0 + 16) = (float4){a01[0] * inv0, a01[1] * inv0, a01[2] * inv0, a01[3] * inv0};
    *(float4*)ob1        = (float4){a10[0] * inv1, a10[1] * inv1, a10[2] * inv1, a10[3] * inv1};
    *(float4*)(ob1 + 16) = (float4){a11[0] * inv1, a11[1] * inv1, a11[2] * inv1, a11[3] * inv1};
  }
}

// ================= k_tail: fused combine+xfeat + final ======================
// Block = 8 rows. Phase 1 (cxf): wave w reduces rows 2w,2w+1 -> XA/XS1 in LDS.
// Phase 2 (final): out[8][1024] = XA·A1T + XS1·A2T, A1T/A2T hoisted per-f.
__global__ void __launch_bounds__(256) k_tail(const float* __restrict__ OH,
    const float* __restrict__ dl, const float* __restrict__ FS,
    const float* __restrict__ FD, const float* __restrict__ A1T,
    const float* __restrict__ A2T, float* __restrict__ out) {
  __shared__ float XAs[8][16];
  __shared__ float XS1s[8][16];
  const int t = threadIdx.x;
  const int w = t >> 6, lane = t & 63;
  const int rbase = blockIdx.x * 8;           // 512 blocks
  {
    const float lam0 = dl[lane >> 3];
    const float lam1 = dl[8 + (lane >> 3)];
    const float* oh0 = OH + (size_t)(rbase + w * 2) * 1024;
    float4 y1a0 = *(const float4*)(oh0 + lane * 4);
    float4 y1b0 = *(const float4*)(oh0 + 256 + lane * 4);
    float4 y2a0 = *(const float4*)(oh0 + 512 + lane * 4);
    float4 y2b0 = *(const float4*)(oh0 + 768 + lane * 4);
    float4 y1a1 = *(const float4*)(oh0 + 1024 + lane * 4);
    float4 y1b1 = *(const float4*)(oh0 + 1280 + lane * 4);
    float4 y2a1 = *(const float4*)(oh0 + 1536 + lane * 4);
    float4 y2b1 = *(const float4*)(oh0 + 1792 + lane * 4);
    y2a0.x *= lam0; y2a0.y *= lam0; y2a0.z *= lam0; y2a0.w *= lam0;
    y2b0.x *= lam1; y2b0.y *= lam1; y2b0.z *= lam1; y2b0.w *= lam1;
    y2a1.x *= lam0; y2a1.y *= lam0; y2a1.z *= lam0; y2a1.w *= lam0;
    y2b1.x *= lam1; y2b1.y *= lam1; y2b1.z *= lam1; y2b1.w *= lam1;
    float acc0[16], acc1[16];
    #pragma unroll
    for (int f = 0; f < 16; ++f) {
      float4 sa = *(const float4*)(FS + f * 512 + lane * 4);
      float4 sb = *(const float4*)(FS + f * 512 + 256 + lane * 4);
      float4 da = *(const float4*)(FD + f * 512 + lane * 4);
      float4 db = *(const float4*)(FD + f * 512 + 256 + lane * 4);
      acc0[f] = dot4(y1a0, sa) + dot4(y1b0, sb) + dot4(y2a0, da) + dot4(y2b0, db);
      acc1[f] = dot4(y1a1, sa) + dot4(y1b1, sb) + dot4(y2a1, da) + dot4(y2b1, db);
    }
    #pragma unroll
    for (int f = 0; f < 16; ++f) {
      #pragma unroll
      for (int off = 32; off >= 1; off >>= 1) {
        acc0[f] += __shfl_xor(acc0[f], off);
        acc1[f] += __shfl_xor(acc1[f], off);
      }
    }
    if (lane == 0) {
      #pragma unroll
      for (int f = 0; f < 16; ++f) {
        float xf = acc0[f];
        float xs = 1.0f / (1.0f + expf(-5.0f * xf));
        XAs[w * 2][f] = xf * xs;
        XS1s[w * 2][f] = 1.0f - xs;
        float xg = acc1[f];
        float xt = 1.0f / (1.0f + expf(-5.0f * xg));
        XAs[w * 2 + 1][f] = xg * xt;
        XS1s[w * 2 + 1][f] = 1.0f - xt;
      }
    }
  }
  __syncthreads();
  {
    float4 acc[8];
    #pragma unroll
    for (int rr = 0; rr < 8; ++rr) acc[rr] = (float4){0.f, 0.f, 0.f, 0.f};
    #pragma unroll
    for (int f = 0; f < 16; ++f) {
      float4 a1 = *(const float4*)(A1T + f * 1024 + t * 4);
      float4 a2 = *(const float4*)(A2T + f * 1024 + t * 4);
      #pragma unroll
      for (int rr = 0; rr < 8; ++rr) {
        float xa = XAs[rr][f], x1 = XS1s[rr][f];
        acc[rr].x = fmaf(xa, a1.x, fmaf(x1, a2.x, acc[rr].x));
        acc[rr].y = fmaf(xa, a1.y, fmaf(x1, a2.y, acc[rr].y));
        acc[rr].z = fmaf(xa, a1.z, fmaf(x1, a2.z, acc[rr].z));
        acc[rr].w = fmaf(xa, a1.w, fmaf(x1, a2.w, acc[rr].w));
      }
    }
    #pragma unroll
    for (int rr = 0; rr < 8; ++rr)
      *(float4*)(out + (size_t)(rbase + rr) * 1024 + t * 4) = acc[rr];
  }
}

extern "C" void kernel_launch(void* const* d_in, const int* in_sizes, int n_in,
                              void* d_out, int out_size, void* d_ws, size_t ws_size,
                              hipStream_t stream) {
  const float* x      = (const float*)d_in[0];
  const float* w_qkv  = (const float*)d_in[1];
  const float* feats  = (const float*)d_in[2];
  const float* protos = (const float*)d_in[3];
  const float* theta  = (const float*)d_in[4];
  const float* alpha  = (const float*)d_in[5];
  const float* beta   = (const float*)d_in[6];
  const float* q_gain = (const float*)d_in[7];
  const float* dlam   = (const float*)d_in[8];
  float* out = (float*)d_out;
  float* ws  = (float*)d_ws;

  // workspace layout
  float* QKV = ws;                    // 12,582,912
  float* OH  = QKV + 12582912;        // 4,194,304
  float* COS = OH  + 4194304;         // 65,536
  float* SIN = COS + 65536;           // 65,536
  float* PT  = SIN + 65536;           // 1,048,576
  float* A1T = PT  + 1048576;         // 16,384
  float* A2T = A1T + 16384;           // 16,384
  float* XA  = A2T + 16384;           // 65,536 (unused, kept for layout)
  float* XS1 = XA  + 65536;           // 65,536 (unused)
  unsigned short* QB16 = (unsigned short*)(XS1 + 65536);  // 4,194,304
  unsigned short* KB16 = QB16 + 4194304;                  // 4,194,304
  unsigned short* VT16 = KB16 + 4194304;                  // 4,194,304
  unsigned short* Wb   = VT16 + 4194304;                  // 3,145,728
  unsigned short* Xhi  = Wb   + 3145728;                  // 4,194,304
  unsigned short* Xlo  = Xhi  + 4194304;                  // 4,194,304
  float* FS = (float*)(Xlo + 4194304);                    // 8,192
  float* FD = FS + 8192;                                  // 8,192

  k_prep<<<20768, 256, 0, stream>>>(w_qkv, protos, x, feats, Wb, PT,
                                    Xhi, Xlo, COS, SIN, FS, FD);
  k_gemm4<<<256, 512, 0, stream>>>(Xhi, Xlo, Wb, QKV);
  k_mid<<<35072, 256, 0, stream>>>(QKV, COS, SIN, q_gain, QB16, KB16, VT16,
                                   PT, feats, theta, alpha, beta, A1T, A2T);
  k_attn<<<4096, 256, 0, stream>>>(QB16, KB16, VT16, OH);
  k_tail<<<512, 256, 0, stream>>>(OH, dlam, FS, FD, A1T, A2T, out);
}

// Round 6
// 242.640 us; speedup vs baseline: 1.2047x; 1.2047x over previous
//
#include <hip/hip_runtime.h>
#include <hip/hip_bf16.h>
#include <math.h>

// Problem constants
#define DIM   1024
#define NHEAD 16
#define SLEN  2048
#define BATCH 2
#define NROWS (BATCH*SLEN)   // 4096
#define QKV_N 3072

typedef __attribute__((ext_vector_type(8))) short short8v;
typedef __attribute__((ext_vector_type(4))) short short4v;
typedef __attribute__((ext_vector_type(4))) float f32x4;
typedef __attribute__((ext_vector_type(4))) unsigned int u32x4;

// RNE float->bf16 bit tricks (valid for finite, non-overflowing inputs —
// identical result to __float2bfloat16 / jnp astype for our value ranges)
__device__ __forceinline__ unsigned short rne16(float f) {
  unsigned u = __float_as_uint(f);
  u += 0x7FFFu + ((u >> 16) & 1u);
  return (unsigned short)(u >> 16);
}
__device__ __forceinline__ float rnef(float f) {
  unsigned u = __float_as_uint(f);
  u += 0x7FFFu + ((u >> 16) & 1u);
  return __uint_as_float(u & 0xFFFF0000u);
}
// pack two floats as bf16 pair (RNE), low = a, high = b.
// v_cvt_pk_bf16_f32 is RNE on gfx950 -> bit-identical to the bit-trick pk2.
__device__ __forceinline__ unsigned pk2(float a, float b) {
  unsigned r;
  asm("v_cvt_pk_bf16_f32 %0, %1, %2" : "=v"(r) : "v"(a), "v"(b));
  return r;
}

// async global->LDS, 16 bytes per lane; LDS dest = wave-uniform base + lane*16
__device__ __forceinline__ void gld16(const unsigned short* g, unsigned short* l) {
  __builtin_amdgcn_global_load_lds(
      (const __attribute__((address_space(1))) unsigned int*)g,
      (__attribute__((address_space(3))) unsigned int*)l, 16, 0, 0);
}

// ================= k_prep: all independent input transforms =================
// blocks [0,12288)        ternary(w_qkv) -> bf16 Wb
// blocks [12288,16384)    ternary(protos) -> fp32 PT
// blocks [16384,20480)    xsplit (x -> Xhi,Xlo)
// blocks [20480,20736)    rope tables
// blocks [20736,20768)    feature split FS/FD
__global__ void __launch_bounds__(256) k_prep(
    const float* __restrict__ w_qkv, const float* __restrict__ protos,
    const float* __restrict__ x, const float* __restrict__ F,
    unsigned short* __restrict__ Wb, float* __restrict__ PT,
    unsigned short* __restrict__ Xhi, unsigned short* __restrict__ Xlo,
    float* __restrict__ cosT, float* __restrict__ sinT,
    float* __restrict__ FS, float* __restrict__ FD) {
  const int blk = blockIdx.x, tid = threadIdx.x;
  if (blk < 12288) {                       // ternary -> bf16
    int idx = blk * 256 + tid;
    float wb = rnef(w_qkv[idx]);
    float a = fabsf(wb);
    #pragma unroll
    for (int off = 32; off >= 1; off >>= 1) a += __shfl_xor(a, off);
    float scale = fmaxf(rnef(a * (1.0f / 64.0f)), 1e-8f);
    float q = fminf(1.0f, fmaxf(-1.0f, rintf(rnef(wb / scale))));
    float deq = rnef(q * scale);
    float d = rnef(deq - wb);
    Wb[idx] = rne16(wb + d);
  } else if (blk < 16384) {                // ternary -> fp32 (prototypes)
    int idx = (blk - 12288) * 256 + tid;
    float wb = rnef(protos[idx]);
    float a = fabsf(wb);
    #pragma unroll
    for (int off = 32; off >= 1; off >>= 1) a += __shfl_xor(a, off);
    float scale = fmaxf(rnef(a * (1.0f / 64.0f)), 1e-8f);
    float q = fminf(1.0f, fmaxf(-1.0f, rintf(rnef(wb / scale))));
    float deq = rnef(q * scale);
    float d = rnef(deq - wb);
    PT[idx] = rnef(wb + d);
  } else if (blk < 20480) {                // xsplit
    int idx = (blk - 16384) * 256 + tid;
    float4 v = *(const float4*)(x + (size_t)idx * 4);
    short4v hi, lo;
    float h0 = rnef(v.x); hi[0] = (short)rne16(v.x); lo[0] = (short)rne16(v.x - h0);
    float h1 = rnef(v.y); hi[1] = (short)rne16(v.y); lo[1] = (short)rne16(v.y - h1);
    float h2 = rnef(v.z); hi[2] = (short)rne16(v.z); lo[2] = (short)rne16(v.z - h2);
    float h3 = rnef(v.w); hi[3] = (short)rne16(v.w); lo[3] = (short)rne16(v.w - h3);
    *(short4v*)(Xhi + (size_t)idx * 4) = hi;
    *(short4v*)(Xlo + (size_t)idx * 4) = lo;
  } else if (blk < 20736) {                // rope tables
    int idx = (blk - 20480) * 256 + tid;   // 65536
    int s = idx >> 5, j = idx & 31;
    double inv  = 1.0 / pow(10000.0, (double)(2 * j) / 64.0);
    double ramp = ((double)(2 * j) / 64.0 - 0.25) / 0.75;
    ramp = ramp < 0.0 ? 0.0 : (ramp > 1.0 ? 1.0 : ramp);
    inv /= (ramp * 3.0 + 1.0);
    float freq = (float)s * (float)inv;
    cosT[idx] = (float)cos((double)freq);
    sinT[idx] = (float)sin((double)freq);
  } else {                                 // fsplit
    int idx = (blk - 20736) * 256 + tid;   // 8192
    int f = idx >> 9, hd = idx & 511;
    int h = hd >> 5, d = hd & 31;
    float a = F[f * 1024 + h * 64 + d];
    float b = F[f * 1024 + h * 64 + 32 + d];
    FS[idx] = a + b;
    FD[idx] = b - a;
  }
}

// ===== 256x192 shared-B 4-phase bf16 MFMA GEMM =====
// C[4096][3072] = (Xhi+Xlo)·Wb^T. grid 16x16 = 256 blocks (all CUs busy).
// Per iteration (kc = i*64): B(kc) staged once (dbuf), read once to regs,
// reused by 4 phases: (qm0,hi),(qm1,hi),(qm0,lo),(qm1,lo), 24 MFMA each.
// A single-buffered with half-granularity overwrite (half freed 1 phase
// before restage; every stage->read pair has >=3 phases landing margin).
// LDS 112 KiB: AHI 32K | ALO 32K | B 2x24K, st_16x32 XOR swizzle.
// Counted vmcnt at phase ends: 4/4/7/7 steady-state, never 0 until drain.
#define FEN() asm volatile("" ::: "memory")
#define SB()  do { FEN(); __builtin_amdgcn_s_barrier(); FEN(); } while (0)
#define WL()  do { asm volatile("s_waitcnt lgkmcnt(0)" ::: "memory"); \
                   __builtin_amdgcn_sched_barrier(0); } while (0)
#define WVN(n) asm volatile("s_waitcnt vmcnt(" #n ")" ::: "memory")

__global__ void __launch_bounds__(512, 2) k_gemm4(
    const unsigned short* __restrict__ Xhi, const unsigned short* __restrict__ Xlo,
    const unsigned short* __restrict__ Wb, float* __restrict__ C) {
  __shared__ unsigned char lds[114688];
  const int t = threadIdx.x;
  const int lane = t & 63;
  const int qL = lane & 15, quad = lane >> 4;
  const int wid = t >> 6;
  const int wm = wid >> 2, wn = wid & 3;   // 2M x 4N waves; per-wave 128x48
  // XCD-aware swizzle: 256 % 8 == 0 -> bijective
  const int bid = blockIdx.x;
  const int swz = (bid & 7) * 32 + (bid >> 3);
  const int by = swz >> 4, bx = swz & 15;
  const int bm = by * 256, bn = bx * 192;
  // swizzled ds_read inner offset (st_16x32 within 1024B subtile)
  const int inner = qL * 64 + ((quad * 16) ^ ((qL & 8) << 2));
  // staging decode: linear dest L -> logical (row, col) via involution P
  int rj[3], cj[3];
  #pragma unroll
  for (int j = 0; j < 3; ++j) {
    int L = j * 8192 + t * 16;
    int Lp = L ^ (((L >> 9) & 1) << 5);
    int st = Lp >> 10;
    rj[j] = (st >> 1) * 16 + ((Lp >> 6) & 15);
    cj[j] = (st & 1) * 32 + ((Lp & 63) >> 1);
  }
  unsigned char* AHI = lds;                 // 2 halves x 16K
  unsigned char* ALO = lds + 32768;         // 2 halves x 16K
  unsigned char* BB  = lds + 65536;         // 2 bufs x 24K

  // stage A half-tile (128 rows interleaved as wm-blocks) of panel at kc
  auto STA = [&](const unsigned short* __restrict__ pan, unsigned char* reg,
                 int kc, int h) {
    unsigned char* lb = reg + h * 16384 + (t >> 6) * 1024;
    #pragma unroll
    for (int j = 0; j < 2; ++j) {
      int rr = bm + ((rj[j] >> 6) * 128) + h * 64 + (rj[j] & 63);
      gld16(pan + (size_t)rr * 1024 + kc + cj[j], (unsigned short*)(lb + j * 8192));
    }
  };
  // stage whole B tile (192 rows) of kc into buf
  auto STB = [&](int kc, int buf) {
    unsigned char* lb = BB + buf * 24576 + (t >> 6) * 1024;
    #pragma unroll
    for (int j = 0; j < 3; ++j)
      gld16(Wb + (size_t)(bn + rj[j]) * 1024 + kc + cj[j],
            (unsigned short*)(lb + j * 8192));
  };

  short8v aF[4][2], bF[3][2];
  f32x4 acc[2][4][3];
  const f32x4 zz = {0.f, 0.f, 0.f, 0.f};
  #pragma unroll
  for (int q_ = 0; q_ < 2; ++q_)
    #pragma unroll
    for (int m_ = 0; m_ < 4; ++m_)
      #pragma unroll
      for (int n_ = 0; n_ < 3; ++n_) acc[q_][m_][n_] = zz;

  auto RA = [&](unsigned char* reg, int qm_) {
    #pragma unroll
    for (int mi = 0; mi < 4; ++mi)
      #pragma unroll
      for (int ks = 0; ks < 2; ++ks)
        aF[mi][ks] = *(const short8v*)(reg + qm_ * 16384 +
                                       ((((wm * 4 + mi) << 1) + ks) << 10) + inner);
  };
  auto RB = [&](int buf) {
    #pragma unroll
    for (int ni = 0; ni < 3; ++ni)
      #pragma unroll
      for (int ks = 0; ks < 2; ++ks)
        bF[ni][ks] = *(const short8v*)(BB + buf * 24576 +
                                       ((((wn * 3 + ni) << 1) + ks) << 10) + inner);
  };
  auto MM = [&](int qm_) {
    __builtin_amdgcn_s_setprio(1);
    #pragma unroll
    for (int ks = 0; ks < 2; ++ks)       // ks outer: dependent pairs 12 apart
      #pragma unroll
      for (int mi = 0; mi < 4; ++mi)
        #pragma unroll
        for (int ni = 0; ni < 3; ++ni)
          acc[qm_][mi][ni] = __builtin_amdgcn_mfma_f32_16x16x32_bf16(
              aF[mi][ks], bF[ni][ks], acc[qm_][mi][ni], 0, 0, 0);
    __builtin_amdgcn_s_setprio(0);
  };

  // prologue: B(0) + Ahi halves + Alo-h0 (9 units); leave newest 4 in flight
  STB(0, 0); STA(Xhi, AHI, 0, 0); STA(Xhi, AHI, 0, 1); STA(Xlo, ALO, 0, 0);
  WVN(4);
  SB();

  #pragma unroll 1
  for (int i = 0; i < 16; ++i) {
    const int kc = i * 64, kn = kc + 64;
    const bool nl = (i < 15);
    const int cb = i & 1, nb = cb ^ 1;
    // ph1: (qm0, hi) — read B once for the whole iteration
    RA(AHI, 0); RB(cb); STA(Xlo, ALO, kc, 1);
    SB(); WL(); MM(0);
    WVN(4);                                   // Ahi-h1(i) landed
    SB();
    // ph2: (qm1, hi)
    RA(AHI, 1);
    if (nl) { STB(kn, nb); STA(Xhi, AHI, kn, 0); }
    SB(); WL(); MM(1);
    if (nl) { WVN(7); } else { WVN(2); }      // Alo-h0(i) landed
    SB();
    // ph3: (qm0, lo)
    RA(ALO, 0);
    if (nl) STA(Xhi, AHI, kn, 1);
    SB(); WL(); MM(0);
    if (nl) { WVN(7); } else { WVN(0); }      // Alo-h1(i) landed
    SB();
    // ph4: (qm1, lo)
    RA(ALO, 1);
    if (nl) STA(Xlo, ALO, kn, 0);
    SB(); WL(); MM(1);
    if (nl) WVN(4);                           // B(i+1), Ahi-h0(i+1) landed
    SB();
  }

  // epilogue: C write (row from A via (quad,reg); col from B via qL)
  #pragma unroll
  for (int qm_ = 0; qm_ < 2; ++qm_)
    #pragma unroll
    for (int mi = 0; mi < 4; ++mi) {
      const int row0 = bm + wm * 128 + qm_ * 64 + mi * 16 + quad * 4;
      #pragma unroll
      for (int ni = 0; ni < 3; ++ni) {
        const int col = bn + wn * 48 + ni * 16 + qL;
        #pragma unroll
        for (int r = 0; r < 4; ++r)
          C[(size_t)(row0 + r) * QKV_N + col] = acc[qm_][mi][ni][r];
      }
    }
}

// ================= k_mid: normrope + vtrans + protproj ======================
// blocks [0,32768)        rmsnorm+rope+gain -> QB16/KB16
// blocks [32768,34816)    V transpose -> VT16 (chunk-permuted layout)
// blocks [34816,35072)    prototype projection -> A1T/A2T
// VT16 layout: row d (stride SLEN); within each 32-key chunk, key kc is
// stored at slot p = 8*((kc&15)>>2) + 4*(kc>>4) + (kc&3) — so the PV
// fragment (zero-shuffle key order) for lane (qL,quad) is 16B contiguous.
__device__ __forceinline__ float dot4(float4 a, float4 b) {
  return fmaf(a.x, b.x, fmaf(a.y, b.y, fmaf(a.z, b.z, a.w * b.w)));
}
__global__ void __launch_bounds__(256) k_mid(const float* __restrict__ QKV,
    const float* __restrict__ cosT, const float* __restrict__ sinT,
    const float* __restrict__ q_gain,
    unsigned short* __restrict__ QB16, unsigned short* __restrict__ KB16,
    unsigned short* __restrict__ VT16,
    const float* __restrict__ PT, const float* __restrict__ F,
    const float* __restrict__ thp, const float* __restrict__ alp,
    const float* __restrict__ bep,
    float* __restrict__ A1T, float* __restrict__ A2T) {
  __shared__ short Vt[64][34];
  const int blk = blockIdx.x, t = threadIdx.x;
  if (blk < 32768) {                       // normrope
    int gid = blk * 256 + t;
    int lane = gid & 63;
    int w = gid >> 6;
    int r = w >> 5;
    int u = w & 31;
    int isk = u >> 4, h = u & 15;
    float x = QKV[(size_t)r * 3072 + isk * 1024 + h * 64 + lane];
    float ss = x * x;
    #pragma unroll
    for (int off = 32; off >= 1; off >>= 1) ss += __shfl_xor(ss, off);
    float xn = x * rsqrtf(ss * (1.0f / 64.0f) + 1e-5f);
    int s = r & (SLEN - 1);
    int b = r >> 11;
    int j = lane & 31;
    float c = cosT[s * 32 + j], sn = sinT[s * 32 + j];
    float other = __shfl_xor(xn, 32);
    float o = (lane < 32) ? fmaf(xn, c, other * sn) : fmaf(xn, c, -other * sn);
    int hh = h + 16 * (lane >> 5);
    int dd = lane & 31;
    size_t addr = (((size_t)(b * 32 + hh) * SLEN) + s) * 32 + dd;
    if (!isk) {
      const float FOLD = 0.17677669529663687f * 1.4426950408889634f;
      QB16[addr] = rne16(o * q_gain[h] * FOLD);
    } else {
      KB16[addr] = rne16(o);
    }
  } else if (blk < 34816) {                // vtrans (chunk-permuted store)
    int i = blk - 32768;
    const int s0 = (i & 31) * 64, hh = (i >> 5) & 31, b = i >> 10;
    const int vcb = 2048 + (hh & 15) * 64 + (hh >> 4) * 32;
    {
      int row = t >> 2, dpart = (t & 3) * 8;
      const float* p = QKV + (size_t)(b * SLEN + s0 + row) * 3072 + vcb + dpart;
      float4 a = *(const float4*)p;
      float4 bq = *(const float4*)(p + 4);
      Vt[row][dpart + 0] = (short)rne16(a.x);  Vt[row][dpart + 1] = (short)rne16(a.y);
      Vt[row][dpart + 2] = (short)rne16(a.z);  Vt[row][dpart + 3] = (short)rne16(a.w);
      Vt[row][dpart + 4] = (short)rne16(bq.x); Vt[row][dpart + 5] = (short)rne16(bq.y);
      Vt[row][dpart + 6] = (short)rne16(bq.z); Vt[row][dpart + 7] = (short)rne16(bq.w);
    }
    __syncthreads();
    {
      int d = t >> 3, j = t & 7;
      short8v v;
      #pragma unroll
      for (int k = 0; k < 8; ++k) v[k] = Vt[j * 8 + k][d];
      // orig keys s0+8j..+7 -> chunk c = (s0>>5)+(j>>2), kc = 8*(j&3)..+7
      // kc block 8m..8m+7 maps to slots {p0..p0+3} u {p0+8..p0+11},
      // p0 = 16*(m&1) + 4*(m>>1)
      const int m = j & 3;
      const int cb = s0 + ((j >> 2) << 5);
      const int p0 = ((m & 1) << 4) + ((m >> 1) << 2);
      unsigned short* basep =
          VT16 + (((size_t)(b * 32 + hh) * 32) + d) * SLEN + cb + p0;
      short4v lo = __builtin_shufflevector(v, v, 0, 1, 2, 3);
      short4v hi = __builtin_shufflevector(v, v, 4, 5, 6, 7);
      *(short4v*)basep = lo;
      *(short4v*)(basep + 8) = hi;
    }
  } else {                                 // protproj (coalesced)
    const int w = t >> 6, lane = t & 63;
    const int o = (blk - 34816) * 4 + w;
    const float* pr = PT + (size_t)o * 1024;
    float4 p0 = *(const float4*)(pr + lane * 4);
    float4 p1 = *(const float4*)(pr + 256 + lane * 4);
    float4 p2 = *(const float4*)(pr + 512 + lane * 4);
    float4 p3 = *(const float4*)(pr + 768 + lane * 4);
    float acc[16];
    #pragma unroll
    for (int f = 0; f < 16; ++f) {
      const float* fr = F + (size_t)f * 1024;
      float4 f0 = *(const float4*)(fr + lane * 4);
      float4 f1 = *(const float4*)(fr + 256 + lane * 4);
      float4 f2 = *(const float4*)(fr + 512 + lane * 4);
      float4 f3 = *(const float4*)(fr + 768 + lane * 4);
      acc[f] = dot4(p0, f0) + dot4(p1, f1) + dot4(p2, f2) + dot4(p3, f3);
    }
    #pragma unroll
    for (int f = 0; f < 16; ++f) {
      #pragma unroll
      for (int off = 32; off >= 1; off >>= 1) acc[f] += __shfl_xor(acc[f], off);
    }
    if (lane == 0) {
      float th = fabsf(*thp), al = fabsf(*alp), be = fabsf(*bep);
      #pragma unroll
      for (int f = 0; f < 16; ++f) {
        float pf = acc[f];
        float ps = 1.0f / (1.0f + expf(-5.0f * pf));
        float pa = pf * ps;
        A1T[f * 1024 + o] = th * pa - al * (1.0f - ps);
        A2T[f * 1024 + o] = -be * pa;
      }
    }
  }
}

// ====== MFMA flash attention: block-shared K/V chunks via LDS ===============
// TA model (R2-R5 data): each global-load inst costs ~64 addr cycles/CU,
// regardless of width/caching -> minimize VMEM instructions per chunk-unit.
// 1024 blocks x 4 waves; wave w owns q-block qb = 4G+w (32 q rows); all 4
// waves iterate the SAME chunks c=0..4G+3. Per chunk the block stages
// K (2KB) + V (2KB) into LDS with 4 gld16 (one per wave, 1KB each) = 1 VMEM
// inst per chunk-unit (was 4-6). LDS uses fragment-linear layout (staging
// SOURCE is per-lane) so every fragment read is ds_read_b128 at lane*16 —
// conflict-free. Zero-shuffle P (R5, bit-exact) -> no P LDS. Double-buffered,
// 1 gld16 in flight, drained after ~300cy of compute. Group sequence G is a
// balanced permutation so any round-robin window of 4 blocks/CU has equal
// total chunks (work varies 16:1 and grid == capacity).
__global__ void __launch_bounds__(256, 6) k_attn(
    const unsigned short* __restrict__ QB16,
    const unsigned short* __restrict__ KB16,
    const unsigned short* __restrict__ VT16,
    float* __restrict__ OH) {
  __shared__ unsigned char kv[2][4096];   // [buf][Kt0 1K | Kt1 1K | Vh0 1K | Vh1 1K]
  const int wid = threadIdx.x >> 6;
  const int lane = threadIdx.x & 63;
  const int qL = lane & 15, quad = lane >> 4;
  const int bk = blockIdx.x;              // 1024
  const int combo = bk & 63;              // XCD-local K/V (combo%8 == bk%8)
  // G sequence {15,14,13,12, 0,1,2,3, 11,10,9,8, 4,5,6,7}: windows of 4
  // spaced 4 apart sum to 30 each -> per-CU chunk totals equalized.
  const int ii = bk >> 6, qd = ii >> 2, rr = ii & 3;
  const int G = (qd & 1) ? (rr + ((qd & 2) << 1)) : (15 - rr - ((qd & 2) << 1));
  const int qbw = 4 * G + wid;            // this wave's q-block
  const int cmax = 4 * G + 3;             // chunks staged per block
  const int b = combo >> 5, hh = combo & 31;
  const int q0 = qbw * 32;

  const unsigned short* QB = QB16 + (size_t)(b * 32 + hh) * SLEN * 32;
  const unsigned short* KB = KB16 + (size_t)(b * 32 + hh) * SLEN * 32;
  const unsigned short* VT = VT16 + (size_t)(b * 32 + hh) * 32 * SLEN;

  const short8v qf0 = *(const short8v*)(QB + (size_t)(q0 + qL) * 32 + quad * 8);
  const short8v qf1 = *(const short8v*)(QB + (size_t)(q0 + 16 + qL) * 32 + quad * 8);
  const f32x4 zz = {0.f, 0.f, 0.f, 0.f};
  f32x4 a00 = zz, a01 = zz, a10 = zz, a11 = zz;
  float l0 = 0.f, l1 = 0.f;

  // staging duty: w0 -> K tile0 (keys 32c+qL), w1 -> K tile1 (keys 32c+16+qL),
  // w2 -> V h0 (d=qL), w3 -> V h1 (d=16+qL). Lane's 16B source == exactly the
  // fragment reader lane (qL,quad) consumes -> LDS read is linear lane*16.
  const unsigned short* sbase = (wid < 2)
      ? KB + (size_t)(wid * 16 + qL) * 32 + quad * 8
      : VT + (size_t)((wid - 2) * 16 + qL) * 2048 + quad * 8;
  const int sstep = (wid < 2) ? 1024 : 32;  // shorts per chunk along source
  unsigned short* d0 = (unsigned short*)(&kv[0][0] + wid * 1024);
  unsigned short* d1 = (unsigned short*)(&kv[1][0] + wid * 1024);

  gld16(sbase, d0);                       // stage chunk 0 -> buf 0
  WVN(0);
  SB();

  #pragma unroll 1
  for (int c = 0; c <= cmax; ++c) {
    const unsigned char* kb = &kv[c & 1][0];
    if (c < cmax) gld16(sbase + (size_t)(c + 1) * sstep, (c & 1) ? d0 : d1);
    if (c <= qbw) {
      short8v kf0 = *(const short8v*)(kb + lane * 16);
      short8v kf1 = *(const short8v*)(kb + 1024 + lane * 16);
      short8v vf0 = *(const short8v*)(kb + 2048 + lane * 16);
      short8v vf1 = *(const short8v*)(kb + 3072 + lane * 16);
      if (c < qbw) {                      // full (unmasked) chunk
        f32x4 s00 = __builtin_amdgcn_mfma_f32_16x16x32_bf16(kf0, qf0, zz, 0, 0, 0);
        f32x4 s01 = __builtin_amdgcn_mfma_f32_16x16x32_bf16(kf1, qf0, zz, 0, 0, 0);
        f32x4 s10 = __builtin_amdgcn_mfma_f32_16x16x32_bf16(kf0, qf1, zz, 0, 0, 0);
        f32x4 s11 = __builtin_amdgcn_mfma_f32_16x16x32_bf16(kf1, qf1, zz, 0, 0, 0);
        float p00[4], p01[4], p10[4], p11[4];
        #pragma unroll
        for (int r = 0; r < 4; ++r) {
          p00[r] = __builtin_amdgcn_exp2f(s00[r]);
          p01[r] = __builtin_amdgcn_exp2f(s01[r]);
          p10[r] = __builtin_amdgcn_exp2f(s10[r]);
          p11[r] = __builtin_amdgcn_exp2f(s11[r]);
        }
        l0 += (p00[0] + p00[1] + p00[2] + p00[3]) + (p01[0] + p01[1] + p01[2] + p01[3]);
        l1 += (p10[0] + p10[1] + p10[2] + p10[3]) + (p11[0] + p11[1] + p11[2] + p11[3]);
        u32x4 up0 = {pk2(p00[0], p00[1]), pk2(p00[2], p00[3]),
                     pk2(p01[0], p01[1]), pk2(p01[2], p01[3])};
        u32x4 up1 = {pk2(p10[0], p10[1]), pk2(p10[2], p10[3]),
                     pk2(p11[0], p11[1]), pk2(p11[2], p11[3])};
        short8v pf0 = __builtin_bit_cast(short8v, up0);
        short8v pf1 = __builtin_bit_cast(short8v, up1);
        a00 = __builtin_amdgcn_mfma_f32_16x16x32_bf16(vf0, pf0, a00, 0, 0, 0);
        a01 = __builtin_amdgcn_mfma_f32_16x16x32_bf16(vf1, pf0, a01, 0, 0, 0);
        a10 = __builtin_amdgcn_mfma_f32_16x16x32_bf16(vf0, pf1, a10, 0, 0, 0);
        a11 = __builtin_amdgcn_mfma_f32_16x16x32_bf16(vf1, pf1, a11, 0, 0, 0);
      } else {                            // tail chunk (diagonal masks)
        f32x4 s00 = __builtin_amdgcn_mfma_f32_16x16x32_bf16(kf0, qf0, zz, 0, 0, 0);
        f32x4 s10 = __builtin_amdgcn_mfma_f32_16x16x32_bf16(kf0, qf1, zz, 0, 0, 0);
        f32x4 s11 = __builtin_amdgcn_mfma_f32_16x16x32_bf16(kf1, qf1, zz, 0, 0, 0);
        float p00[4], p10[4], p11[4];
        #pragma unroll
        for (int r = 0; r < 4; ++r) {
          bool v = (4 * quad + r) <= qL;  // same predicate for s00 and s11
          p00[r] = v ? __builtin_amdgcn_exp2f(s00[r]) : 0.f;
          p10[r] = __builtin_amdgcn_exp2f(s10[r]);   // always valid
          p11[r] = v ? __builtin_amdgcn_exp2f(s11[r]) : 0.f;
        }
        l0 += (p00[0] + p00[1] + p00[2] + p00[3]);
        l1 += (p10[0] + p10[1] + p10[2] + p10[3]) + (p11[0] + p11[1] + p11[2] + p11[3]);
        u32x4 up0 = {pk2(p00[0], p00[1]), pk2(p00[2], p00[3]), 0u, 0u};
        u32x4 up1 = {pk2(p10[0], p10[1]), pk2(p10[2], p10[3]),
                     pk2(p11[0], p11[1]), pk2(p11[2], p11[3])};
        short8v pf0 = __builtin_bit_cast(short8v, up0);
        short8v pf1 = __builtin_bit_cast(short8v, up1);
        a00 = __builtin_amdgcn_mfma_f32_16x16x32_bf16(vf0, pf0, a00, 0, 0, 0);
        a01 = __builtin_amdgcn_mfma_f32_16x16x32_bf16(vf1, pf0, a01, 0, 0, 0);
        a10 = __builtin_amdgcn_mfma_f32_16x16x32_bf16(vf0, pf1, a10, 0, 0, 0);
        a11 = __builtin_amdgcn_mfma_f32_16x16x32_bf16(vf1, pf1, a11, 0, 0, 0);
      }
    }
    if (c < cmax) WVN(0);                 // own gld16 landed (issued ~300cy ago)
    SB();                                 // reads of this buf done before next
  }                                       // iteration's stage overwrites it

  // epilogue: per-wave l reduction + OH write (no cross-wave combine)
  l0 += __shfl_xor(l0, 16); l0 += __shfl_xor(l0, 32);
  l1 += __shfl_xor(l1, 16); l1 += __shfl_xor(l1, 32);
  const float inv0 = 1.0f / l0, inv1 = 1.0f / l1;
  float* ob0 = OH + (((size_t)(b * SLEN + q0 + qL) * 32) + hh) * 32 + (quad << 2);
  float* ob1 = OH + (((size_t)(b * SLEN + q0 + 16 + qL) * 32) + hh) * 32 + (quad << 2);
  *(float4*)ob0        = (float4){a00[0] * inv0, a00[1] * inv0, a00[2] * inv0, a00[3] * inv0};
  *(float4*)(ob0 + 16) = (float4){a01[0] * inv0, a01[1] * inv0, a01[2] * inv0, a01[3] * inv0};
  *(float4*)ob1        = (float4){a10[0] * inv1, a10[1] * inv1, a10[2] * inv1, a10[3] * inv1};
  *(float4*)(ob1 + 16) = (float4){a11[0] * inv1, a11[1] * inv1, a11[2] * inv1, a11[3] * inv1};
}

// ================= k_tail: fused combine+xfeat + final ======================
// Block = 8 rows. Phase 1 (cxf): wave w reduces rows 2w,2w+1 -> XA/XS1 in LDS.
// Phase 2 (final): out[8][1024] = XA·A1T + XS1·A2T, A1T/A2T hoisted per-f.
__global__ void __launch_bounds__(256) k_tail(const float* __restrict__ OH,
    const float* __restrict__ dl, const float* __restrict__ FS,
    const float* __restrict__ FD, const float* __restrict__ A1T,
    const float* __restrict__ A2T, float* __restrict__ out) {
  __shared__ float XAs[8][16];
  __shared__ float XS1s[8][16];
  const int t = threadIdx.x;
  const int w = t >> 6, lane = t & 63;
  const int rbase = blockIdx.x * 8;           // 512 blocks
  {
    const float lam0 = dl[lane >> 3];
    const float lam1 = dl[8 + (lane >> 3)];
    const float* oh0 = OH + (size_t)(rbase + w * 2) * 1024;
    float4 y1a0 = *(const float4*)(oh0 + lane * 4);
    float4 y1b0 = *(const float4*)(oh0 + 256 + lane * 4);
    float4 y2a0 = *(const float4*)(oh0 + 512 + lane * 4);
    float4 y2b0 = *(const float4*)(oh0 + 768 + lane * 4);
    float4 y1a1 = *(const float4*)(oh0 + 1024 + lane * 4);
    float4 y1b1 = *(const float4*)(oh0 + 1280 + lane * 4);
    float4 y2a1 = *(const float4*)(oh0 + 1536 + lane * 4);
    float4 y2b1 = *(const float4*)(oh0 + 1792 + lane * 4);
    y2a0.x *= lam0; y2a0.y *= lam0; y2a0.z *= lam0; y2a0.w *= lam0;
    y2b0.x *= lam1; y2b0.y *= lam1; y2b0.z *= lam1; y2b0.w *= lam1;
    y2a1.x *= lam0; y2a1.y *= lam0; y2a1.z *= lam0; y2a1.w *= lam0;
    y2b1.x *= lam1; y2b1.y *= lam1; y2b1.z *= lam1; y2b1.w *= lam1;
    float acc0[16], acc1[16];
    #pragma unroll
    for (int f = 0; f < 16; ++f) {
      float4 sa = *(const float4*)(FS + f * 512 + lane * 4);
      float4 sb = *(const float4*)(FS + f * 512 + 256 + lane * 4);
      float4 da = *(const float4*)(FD + f * 512 + lane * 4);
      float4 db = *(const float4*)(FD + f * 512 + 256 + lane * 4);
      acc0[f] = dot4(y1a0, sa) + dot4(y1b0, sb) + dot4(y2a0, da) + dot4(y2b0, db);
      acc1[f] = dot4(y1a1, sa) + dot4(y1b1, sb) + dot4(y2a1, da) + dot4(y2b1, db);
    }
    #pragma unroll
    for (int f = 0; f < 16; ++f) {
      #pragma unroll
      for (int off = 32; off >= 1; off >>= 1) {
        acc0[f] += __shfl_xor(acc0[f], off);
        acc1[f] += __shfl_xor(acc1[f], off);
      }
    }
    if (lane == 0) {
      #pragma unroll
      for (int f = 0; f < 16; ++f) {
        float xf = acc0[f];
        float xs = 1.0f / (1.0f + expf(-5.0f * xf));
        XAs[w * 2][f] = xf * xs;
        XS1s[w * 2][f] = 1.0f - xs;
        float xg = acc1[f];
        float xt = 1.0f / (1.0f + expf(-5.0f * xg));
        XAs[w * 2 + 1][f] = xg * xt;
        XS1s[w * 2 + 1][f] = 1.0f - xt;
      }
    }
  }
  __syncthreads();
  {
    float4 acc[8];
    #pragma unroll
    for (int rr = 0; rr < 8; ++rr) acc[rr] = (float4){0.f, 0.f, 0.f, 0.f};
    #pragma unroll
    for (int f = 0; f < 16; ++f) {
      float4 a1 = *(const float4*)(A1T + f * 1024 + t * 4);
      float4 a2 = *(const float4*)(A2T + f * 1024 + t * 4);
      #pragma unroll
      for (int rr = 0; rr < 8; ++rr) {
        float xa = XAs[rr][f], x1 = XS1s[rr][f];
        acc[rr].x = fmaf(xa, a1.x, fmaf(x1, a2.x, acc[rr].x));
        acc[rr].y = fmaf(xa, a1.y, fmaf(x1, a2.y, acc[rr].y));
        acc[rr].z = fmaf(xa, a1.z, fmaf(x1, a2.z, acc[rr].z));
        acc[rr].w = fmaf(xa, a1.w, fmaf(x1, a2.w, acc[rr].w));
      }
    }
    #pragma unroll
    for (int rr = 0; rr < 8; ++rr)
      *(float4*)(out + (size_t)(rbase + rr) * 1024 + t * 4) = acc[rr];
  }
}

extern "C" void kernel_launch(void* const* d_in, const int* in_sizes, int n_in,
                              void* d_out, int out_size, void* d_ws, size_t ws_size,
                              hipStream_t stream) {
  const float* x      = (const float*)d_in[0];
  const float* w_qkv  = (const float*)d_in[1];
  const float* feats  = (const float*)d_in[2];
  const float* protos = (const float*)d_in[3];
  const float* theta  = (const float*)d_in[4];
  const float* alpha  = (const float*)d_in[5];
  const float* beta   = (const float*)d_in[6];
  const float* q_gain = (const float*)d_in[7];
  const float* dlam   = (const float*)d_in[8];
  float* out = (float*)d_out;
  float* ws  = (float*)d_ws;

  // workspace layout
  float* QKV = ws;                    // 12,582,912
  float* OH  = QKV + 12582912;        // 4,194,304
  float* COS = OH  + 4194304;         // 65,536
  float* SIN = COS + 65536;           // 65,536
  float* PT  = SIN + 65536;           // 1,048,576
  float* A1T = PT  + 1048576;         // 16,384
  float* A2T = A1T + 16384;           // 16,384
  float* XA  = A2T + 16384;           // 65,536 (unused, kept for layout)
  float* XS1 = XA  + 65536;           // 65,536 (unused)
  unsigned short* QB16 = (unsigned short*)(XS1 + 65536);  // 4,194,304
  unsigned short* KB16 = QB16 + 4194304;                  // 4,194,304
  unsigned short* VT16 = KB16 + 4194304;                  // 4,194,304
  unsigned short* Wb   = VT16 + 4194304;                  // 3,145,728
  unsigned short* Xhi  = Wb   + 3145728;                  // 4,194,304
  unsigned short* Xlo  = Xhi  + 4194304;                  // 4,194,304
  float* FS = (float*)(Xlo + 4194304);                    // 8,192
  float* FD = FS + 8192;                                  // 8,192

  k_prep<<<20768, 256, 0, stream>>>(w_qkv, protos, x, feats, Wb, PT,
                                    Xhi, Xlo, COS, SIN, FS, FD);
  k_gemm4<<<256, 512, 0, stream>>>(Xhi, Xlo, Wb, QKV);
  k_mid<<<35072, 256, 0, stream>>>(QKV, COS, SIN, q_gain, QB16, KB16, VT16,
                                   PT, feats, theta, alpha, beta, A1T, A2T);
  k_attn<<<1024, 256, 0, stream>>>(QB16, KB16, VT16, OH);
  k_tail<<<512, 256, 0, stream>>>(OH, dlam, FS, FD, A1T, A2T, out);
}

// Round 7
// 220.095 us; speedup vs baseline: 1.3281x; 1.1024x over previous
//
#include <hip/hip_runtime.h>
#include <hip/hip_bf16.h>
#include <math.h>

// Problem constants
#define DIM   1024
#define NHEAD 16
#define SLEN  2048
#define BATCH 2
#define NROWS (BATCH*SLEN)   // 4096
#define QKV_N 3072

typedef __attribute__((ext_vector_type(8))) short short8v;
typedef __attribute__((ext_vector_type(4))) short short4v;
typedef __attribute__((ext_vector_type(4))) float f32x4;
typedef __attribute__((ext_vector_type(4))) unsigned int u32x4;

// RNE float->bf16 bit tricks (valid for finite, non-overflowing inputs —
// identical result to __float2bfloat16 / jnp astype for our value ranges)
__device__ __forceinline__ unsigned short rne16(float f) {
  unsigned u = __float_as_uint(f);
  u += 0x7FFFu + ((u >> 16) & 1u);
  return (unsigned short)(u >> 16);
}
__device__ __forceinline__ float rnef(float f) {
  unsigned u = __float_as_uint(f);
  u += 0x7FFFu + ((u >> 16) & 1u);
  return __uint_as_float(u & 0xFFFF0000u);
}
// pack two floats as bf16 pair (RNE), low = a, high = b.
// v_cvt_pk_bf16_f32 is RNE on gfx950 -> bit-identical to the bit-trick pk2.
__device__ __forceinline__ unsigned pk2(float a, float b) {
  unsigned r;
  asm("v_cvt_pk_bf16_f32 %0, %1, %2" : "=v"(r) : "v"(a), "v"(b));
  return r;
}

// async global->LDS, 16 bytes per lane; LDS dest = wave-uniform base + lane*16
__device__ __forceinline__ void gld16(const unsigned short* g, unsigned short* l) {
  __builtin_amdgcn_global_load_lds(
      (const __attribute__((address_space(1))) unsigned int*)g,
      (__attribute__((address_space(3))) unsigned int*)l, 16, 0, 0);
}

// ================= k_prep: all independent input transforms =================
// blocks [0,3072)      ternary(w_qkv) -> bf16 Wb      (float4/lane)
// blocks [3072,4096)   ternary(protos) -> fp32 PT     (float4/lane)
// blocks [4096,8192)   xsplit (x -> Xhi,Xlo)
// blocks [8192,8448)   rope tables
// blocks [8448,8480)   feature split FS/FD
// Ternary reduction tree is a BIT-EXACT replica of the old 64-lane tree:
// old lane = 4*j + e (j = lane-group index, e = elem); old offsets {32,16,8,4}
// == per-component shfl offsets {8,4,2,1}; old offsets {2,1} == final
// (a0+a2)+(a1+a3). Same values, same association order -> same scale bits.
__global__ void __launch_bounds__(256) k_prep(
    const float* __restrict__ w_qkv, const float* __restrict__ protos,
    const float* __restrict__ x, const float* __restrict__ F,
    unsigned short* __restrict__ Wb, float* __restrict__ PT,
    unsigned short* __restrict__ Xhi, unsigned short* __restrict__ Xlo,
    float* __restrict__ cosT, float* __restrict__ sinT,
    float* __restrict__ FS, float* __restrict__ FD) {
  const int blk = blockIdx.x, tid = threadIdx.x;
  if (blk < 4096) {                        // ternary (w_qkv or protos)
    const bool isw = (blk < 3072);
    const int idx = (isw ? blk * 256 + tid : (blk - 3072) * 256 + tid) * 4;
    const float* src = isw ? w_qkv : protos;
    float4 v = *(const float4*)(src + idx);
    float b0 = rnef(v.x), b1 = rnef(v.y), b2 = rnef(v.z), b3 = rnef(v.w);
    float a0 = fabsf(b0), a1 = fabsf(b1), a2 = fabsf(b2), a3 = fabsf(b3);
    #pragma unroll
    for (int off = 8; off >= 1; off >>= 1) {
      a0 += __shfl_xor(a0, off); a1 += __shfl_xor(a1, off);
      a2 += __shfl_xor(a2, off); a3 += __shfl_xor(a3, off);
    }
    float s = (a0 + a2) + (a1 + a3);
    float scale = fmaxf(rnef(s * (1.0f / 64.0f)), 1e-8f);
    auto tern = [&](float wb) -> float {
      float q = fminf(1.0f, fmaxf(-1.0f, rintf(rnef(wb / scale))));
      float deq = rnef(q * scale);
      float d = rnef(deq - wb);
      return wb + d;
    };
    if (isw) {
      short4v o;
      o[0] = (short)rne16(tern(b0)); o[1] = (short)rne16(tern(b1));
      o[2] = (short)rne16(tern(b2)); o[3] = (short)rne16(tern(b3));
      *(short4v*)(Wb + idx) = o;
    } else {
      float4 o = {rnef(tern(b0)), rnef(tern(b1)), rnef(tern(b2)), rnef(tern(b3))};
      *(float4*)(PT + idx) = o;
    }
  } else if (blk < 8192) {                 // xsplit
    int idx = (blk - 4096) * 256 + tid;
    float4 v = *(const float4*)(x + (size_t)idx * 4);
    short4v hi, lo;
    float h0 = rnef(v.x); hi[0] = (short)rne16(v.x); lo[0] = (short)rne16(v.x - h0);
    float h1 = rnef(v.y); hi[1] = (short)rne16(v.y); lo[1] = (short)rne16(v.y - h1);
    float h2 = rnef(v.z); hi[2] = (short)rne16(v.z); lo[2] = (short)rne16(v.z - h2);
    float h3 = rnef(v.w); hi[3] = (short)rne16(v.w); lo[3] = (short)rne16(v.w - h3);
    *(short4v*)(Xhi + (size_t)idx * 4) = hi;
    *(short4v*)(Xlo + (size_t)idx * 4) = lo;
  } else if (blk < 8448) {                 // rope tables
    int idx = (blk - 8192) * 256 + tid;    // 65536
    int s = idx >> 5, j = idx & 31;
    double inv  = 1.0 / pow(10000.0, (double)(2 * j) / 64.0);
    double ramp = ((double)(2 * j) / 64.0 - 0.25) / 0.75;
    ramp = ramp < 0.0 ? 0.0 : (ramp > 1.0 ? 1.0 : ramp);
    inv /= (ramp * 3.0 + 1.0);
    float freq = (float)s * (float)inv;
    cosT[idx] = (float)cos((double)freq);
    sinT[idx] = (float)sin((double)freq);
  } else {                                 // fsplit
    int idx = (blk - 8448) * 256 + tid;    // 8192
    int f = idx >> 9, hd = idx & 511;
    int h = hd >> 5, d = hd & 31;
    float a = F[f * 1024 + h * 64 + d];
    float b = F[f * 1024 + h * 64 + 32 + d];
    FS[idx] = a + b;
    FD[idx] = b - a;
  }
}

// ===== 256x192 shared-B 4-phase bf16 MFMA GEMM =====
// C[4096][3072] = (Xhi+Xlo)·Wb^T. grid 16x16 = 256 blocks (all CUs busy).
// Per iteration (kc = i*64): B(kc) staged once (dbuf), read once to regs,
// reused by 4 phases: (qm0,hi),(qm1,hi),(qm0,lo),(qm1,lo), 24 MFMA each.
// A single-buffered with half-granularity overwrite (half freed 1 phase
// before restage; every stage->read pair has >=3 phases landing margin).
// LDS 112 KiB: AHI 32K | ALO 32K | B 2x24K, st_16x32 XOR swizzle.
// Counted vmcnt at phase ends: 4/4/7/7 steady-state, never 0 until drain.
#define FEN() asm volatile("" ::: "memory")
#define SB()  do { FEN(); __builtin_amdgcn_s_barrier(); FEN(); } while (0)
#define WL()  do { asm volatile("s_waitcnt lgkmcnt(0)" ::: "memory"); \
                   __builtin_amdgcn_sched_barrier(0); } while (0)
#define WVN(n) asm volatile("s_waitcnt vmcnt(" #n ")" ::: "memory")

__global__ void __launch_bounds__(512, 2) k_gemm4(
    const unsigned short* __restrict__ Xhi, const unsigned short* __restrict__ Xlo,
    const unsigned short* __restrict__ Wb, float* __restrict__ C) {
  __shared__ unsigned char lds[114688];
  const int t = threadIdx.x;
  const int lane = t & 63;
  const int qL = lane & 15, quad = lane >> 4;
  const int wid = t >> 6;
  const int wm = wid >> 2, wn = wid & 3;   // 2M x 4N waves; per-wave 128x48
  // XCD-aware swizzle: 256 % 8 == 0 -> bijective
  const int bid = blockIdx.x;
  const int swz = (bid & 7) * 32 + (bid >> 3);
  const int by = swz >> 4, bx = swz & 15;
  const int bm = by * 256, bn = bx * 192;
  // swizzled ds_read inner offset (st_16x32 within 1024B subtile)
  const int inner = qL * 64 + ((quad * 16) ^ ((qL & 8) << 2));
  // staging decode: linear dest L -> logical (row, col) via involution P
  int rj[3], cj[3];
  #pragma unroll
  for (int j = 0; j < 3; ++j) {
    int L = j * 8192 + t * 16;
    int Lp = L ^ (((L >> 9) & 1) << 5);
    int st = Lp >> 10;
    rj[j] = (st >> 1) * 16 + ((Lp >> 6) & 15);
    cj[j] = (st & 1) * 32 + ((Lp & 63) >> 1);
  }
  unsigned char* AHI = lds;                 // 2 halves x 16K
  unsigned char* ALO = lds + 32768;         // 2 halves x 16K
  unsigned char* BB  = lds + 65536;         // 2 bufs x 24K

  // stage A half-tile (128 rows interleaved as wm-blocks) of panel at kc
  auto STA = [&](const unsigned short* __restrict__ pan, unsigned char* reg,
                 int kc, int h) {
    unsigned char* lb = reg + h * 16384 + (t >> 6) * 1024;
    #pragma unroll
    for (int j = 0; j < 2; ++j) {
      int rr = bm + ((rj[j] >> 6) * 128) + h * 64 + (rj[j] & 63);
      gld16(pan + (size_t)rr * 1024 + kc + cj[j], (unsigned short*)(lb + j * 8192));
    }
  };
  // stage whole B tile (192 rows) of kc into buf
  auto STB = [&](int kc, int buf) {
    unsigned char* lb = BB + buf * 24576 + (t >> 6) * 1024;
    #pragma unroll
    for (int j = 0; j < 3; ++j)
      gld16(Wb + (size_t)(bn + rj[j]) * 1024 + kc + cj[j],
            (unsigned short*)(lb + j * 8192));
  };

  short8v aF[4][2], bF[3][2];
  f32x4 acc[2][4][3];
  const f32x4 zz = {0.f, 0.f, 0.f, 0.f};
  #pragma unroll
  for (int q_ = 0; q_ < 2; ++q_)
    #pragma unroll
    for (int m_ = 0; m_ < 4; ++m_)
      #pragma unroll
      for (int n_ = 0; n_ < 3; ++n_) acc[q_][m_][n_] = zz;

  auto RA = [&](unsigned char* reg, int qm_) {
    #pragma unroll
    for (int mi = 0; mi < 4; ++mi)
      #pragma unroll
      for (int ks = 0; ks < 2; ++ks)
        aF[mi][ks] = *(const short8v*)(reg + qm_ * 16384 +
                                       ((((wm * 4 + mi) << 1) + ks) << 10) + inner);
  };
  auto RB = [&](int buf) {
    #pragma unroll
    for (int ni = 0; ni < 3; ++ni)
      #pragma unroll
      for (int ks = 0; ks < 2; ++ks)
        bF[ni][ks] = *(const short8v*)(BB + buf * 24576 +
                                       ((((wn * 3 + ni) << 1) + ks) << 10) + inner);
  };
  auto MM = [&](int qm_) {
    __builtin_amdgcn_s_setprio(1);
    #pragma unroll
    for (int ks = 0; ks < 2; ++ks)       // ks outer: dependent pairs 12 apart
      #pragma unroll
      for (int mi = 0; mi < 4; ++mi)
        #pragma unroll
        for (int ni = 0; ni < 3; ++ni)
          acc[qm_][mi][ni] = __builtin_amdgcn_mfma_f32_16x16x32_bf16(
              aF[mi][ks], bF[ni][ks], acc[qm_][mi][ni], 0, 0, 0);
    __builtin_amdgcn_s_setprio(0);
  };

  // prologue: B(0) + Ahi halves + Alo-h0 (9 units); leave newest 4 in flight
  STB(0, 0); STA(Xhi, AHI, 0, 0); STA(Xhi, AHI, 0, 1); STA(Xlo, ALO, 0, 0);
  WVN(4);
  SB();

  #pragma unroll 1
  for (int i = 0; i < 16; ++i) {
    const int kc = i * 64, kn = kc + 64;
    const bool nl = (i < 15);
    const int cb = i & 1, nb = cb ^ 1;
    // ph1: (qm0, hi) — read B once for the whole iteration
    RA(AHI, 0); RB(cb); STA(Xlo, ALO, kc, 1);
    SB(); WL(); MM(0);
    WVN(4);                                   // Ahi-h1(i) landed
    SB();
    // ph2: (qm1, hi)
    RA(AHI, 1);
    if (nl) { STB(kn, nb); STA(Xhi, AHI, kn, 0); }
    SB(); WL(); MM(1);
    if (nl) { WVN(7); } else { WVN(2); }      // Alo-h0(i) landed
    SB();
    // ph3: (qm0, lo)
    RA(ALO, 0);
    if (nl) STA(Xhi, AHI, kn, 1);
    SB(); WL(); MM(0);
    if (nl) { WVN(7); } else { WVN(0); }      // Alo-h1(i) landed
    SB();
    // ph4: (qm1, lo)
    RA(ALO, 1);
    if (nl) STA(Xlo, ALO, kn, 0);
    SB(); WL(); MM(1);
    if (nl) WVN(4);                           // B(i+1), Ahi-h0(i+1) landed
    SB();
  }

  // epilogue: C write (row from A via (quad,reg); col from B via qL)
  #pragma unroll
  for (int qm_ = 0; qm_ < 2; ++qm_)
    #pragma unroll
    for (int mi = 0; mi < 4; ++mi) {
      const int row0 = bm + wm * 128 + qm_ * 64 + mi * 16 + quad * 4;
      #pragma unroll
      for (int ni = 0; ni < 3; ++ni) {
        const int col = bn + wn * 48 + ni * 16 + qL;
        #pragma unroll
        for (int r = 0; r < 4; ++r)
          C[(size_t)(row0 + r) * QKV_N + col] = acc[qm_][mi][ni][r];
      }
    }
}

// ================= k_mid: normrope + vtrans + protproj ======================
// blocks [0,8192)      rmsnorm+rope+gain -> QB16/KB16 (float4/lane; wave = 4
//                      head-units of one row; 16-lane groups own one head)
// blocks [8192,10240)  V transpose -> VT16 (chunk-permuted layout)
// blocks [10240,10496) prototype projection -> A1T/A2T
// RMS reduction tree is a BIT-EXACT replica of the old 64-lane tree (old
// offsets {32,16,8,4} == per-component {8,4,2,1}; {2,1} == (s0+s2)+(s1+s3)).
// VT16 layout: row d (stride SLEN); within each 32-key chunk, key kc is
// stored at slot p = 8*((kc&15)>>2) + 4*(kc>>4) + (kc&3) — so the PV
// fragment (zero-shuffle key order) for lane (qL,quad) is 16B contiguous.
__device__ __forceinline__ float dot4(float4 a, float4 b) {
  return fmaf(a.x, b.x, fmaf(a.y, b.y, fmaf(a.z, b.z, a.w * b.w)));
}
__global__ void __launch_bounds__(256) k_mid(const float* __restrict__ QKV,
    const float* __restrict__ cosT, const float* __restrict__ sinT,
    const float* __restrict__ q_gain,
    unsigned short* __restrict__ QB16, unsigned short* __restrict__ KB16,
    unsigned short* __restrict__ VT16,
    const float* __restrict__ PT, const float* __restrict__ F,
    const float* __restrict__ thp, const float* __restrict__ alp,
    const float* __restrict__ bep,
    float* __restrict__ A1T, float* __restrict__ A2T) {
  __shared__ short Vt[64][34];
  const int blk = blockIdx.x, t = threadIdx.x;
  if (blk < 8192) {                        // normrope (float4/lane)
    int gid = blk * 256 + t;
    int l = gid & 63;
    int w = gid >> 6;                      // 32768 waves
    int r = w >> 3;                        // row 0..4095
    int u = (w & 7) * 4 + (l >> 4);        // head-unit 0..31 (wave-uniform isk)
    int isk = u >> 4, h = u & 15;
    int d0 = (l & 15) * 4;
    float4 xv = *(const float4*)(QKV + (size_t)r * 3072 + isk * 1024 + h * 64 + d0);
    float s0 = xv.x * xv.x, s1 = xv.y * xv.y;
    float s2 = xv.z * xv.z, s3 = xv.w * xv.w;
    #pragma unroll
    for (int off = 8; off >= 1; off >>= 1) {
      s0 += __shfl_xor(s0, off); s1 += __shfl_xor(s1, off);
      s2 += __shfl_xor(s2, off); s3 += __shfl_xor(s3, off);
    }
    float ss = (s0 + s2) + (s1 + s3);
    float inv = rsqrtf(ss * (1.0f / 64.0f) + 1e-5f);
    float xn0 = xv.x * inv, xn1 = xv.y * inv;
    float xn2 = xv.z * inv, xn3 = xv.w * inv;
    int s = r & (SLEN - 1);
    int b = r >> 11;
    int j4 = (l & 7) * 4;
    float4 c4 = *(const float4*)(cosT + s * 32 + j4);
    float4 n4 = *(const float4*)(sinT + s * 32 + j4);
    float ot0 = __shfl_xor(xn0, 8), ot1 = __shfl_xor(xn1, 8);
    float ot2 = __shfl_xor(xn2, 8), ot3 = __shfl_xor(xn3, 8);
    const bool hi = (l & 8) != 0;          // dims >= 32 within head
    float o0 = hi ? fmaf(xn0, c4.x, -ot0 * n4.x) : fmaf(xn0, c4.x, ot0 * n4.x);
    float o1 = hi ? fmaf(xn1, c4.y, -ot1 * n4.y) : fmaf(xn1, c4.y, ot1 * n4.y);
    float o2 = hi ? fmaf(xn2, c4.z, -ot2 * n4.z) : fmaf(xn2, c4.z, ot2 * n4.z);
    float o3 = hi ? fmaf(xn3, c4.w, -ot3 * n4.w) : fmaf(xn3, c4.w, ot3 * n4.w);
    int hh = h + (hi ? 16 : 0);
    size_t addr = (((size_t)(b * 32 + hh) * SLEN) + s) * 32 + (l & 7) * 4;
    short4v o;
    if (!isk) {
      const float FOLD = 0.17677669529663687f * 1.4426950408889634f;
      float g = q_gain[h];
      o[0] = (short)rne16(o0 * g * FOLD); o[1] = (short)rne16(o1 * g * FOLD);
      o[2] = (short)rne16(o2 * g * FOLD); o[3] = (short)rne16(o3 * g * FOLD);
      *(short4v*)(QB16 + addr) = o;
    } else {
      o[0] = (short)rne16(o0); o[1] = (short)rne16(o1);
      o[2] = (short)rne16(o2); o[3] = (short)rne16(o3);
      *(short4v*)(KB16 + addr) = o;
    }
  } else if (blk < 10240) {                // vtrans (chunk-permuted store)
    int i = blk - 8192;
    const int s0 = (i & 31) * 64, hh = (i >> 5) & 31, b = i >> 10;
    const int vcb = 2048 + (hh & 15) * 64 + (hh >> 4) * 32;
    {
      int row = t >> 2, dpart = (t & 3) * 8;
      const float* p = QKV + (size_t)(b * SLEN + s0 + row) * 3072 + vcb + dpart;
      float4 a = *(const float4*)p;
      float4 bq = *(const float4*)(p + 4);
      Vt[row][dpart + 0] = (short)rne16(a.x);  Vt[row][dpart + 1] = (short)rne16(a.y);
      Vt[row][dpart + 2] = (short)rne16(a.z);  Vt[row][dpart + 3] = (short)rne16(a.w);
      Vt[row][dpart + 4] = (short)rne16(bq.x); Vt[row][dpart + 5] = (short)rne16(bq.y);
      Vt[row][dpart + 6] = (short)rne16(bq.z); Vt[row][dpart + 7] = (short)rne16(bq.w);
    }
    __syncthreads();
    {
      int d = t >> 3, j = t & 7;
      short8v v;
      #pragma unroll
      for (int k = 0; k < 8; ++k) v[k] = Vt[j * 8 + k][d];
      // orig keys s0+8j..+7 -> chunk c = (s0>>5)+(j>>2), kc = 8*(j&3)..+7
      // kc block 8m..8m+7 maps to slots {p0..p0+3} u {p0+8..p0+11},
      // p0 = 16*(m&1) + 4*(m>>1)
      const int m = j & 3;
      const int cb = s0 + ((j >> 2) << 5);
      const int p0 = ((m & 1) << 4) + ((m >> 1) << 2);
      unsigned short* basep =
          VT16 + (((size_t)(b * 32 + hh) * 32) + d) * SLEN + cb + p0;
      short4v lo = __builtin_shufflevector(v, v, 0, 1, 2, 3);
      short4v hi = __builtin_shufflevector(v, v, 4, 5, 6, 7);
      *(short4v*)basep = lo;
      *(short4v*)(basep + 8) = hi;
    }
  } else {                                 // protproj (coalesced)
    const int w = t >> 6, lane = t & 63;
    const int o = (blk - 10240) * 4 + w;
    const float* pr = PT + (size_t)o * 1024;
    float4 p0 = *(const float4*)(pr + lane * 4);
    float4 p1 = *(const float4*)(pr + 256 + lane * 4);
    float4 p2 = *(const float4*)(pr + 512 + lane * 4);
    float4 p3 = *(const float4*)(pr + 768 + lane * 4);
    float acc[16];
    #pragma unroll
    for (int f = 0; f < 16; ++f) {
      const float* fr = F + (size_t)f * 1024;
      float4 f0 = *(const float4*)(fr + lane * 4);
      float4 f1 = *(const float4*)(fr + 256 + lane * 4);
      float4 f2 = *(const float4*)(fr + 512 + lane * 4);
      float4 f3 = *(const float4*)(fr + 768 + lane * 4);
      acc[f] = dot4(p0, f0) + dot4(p1, f1) + dot4(p2, f2) + dot4(p3, f3);
    }
    #pragma unroll
    for (int f = 0; f < 16; ++f) {
      #pragma unroll
      for (int off = 32; off >= 1; off >>= 1) acc[f] += __shfl_xor(acc[f], off);
    }
    if (lane == 0) {
      float th = fabsf(*thp), al = fabsf(*alp), be = fabsf(*bep);
      #pragma unroll
      for (int f = 0; f < 16; ++f) {
        float pf = acc[f];
        float ps = 1.0f / (1.0f + expf(-5.0f * pf));
        float pa = pf * ps;
        A1T[f * 1024 + o] = th * pa - al * (1.0f - ps);
        A2T[f * 1024 + o] = -be * pa;
      }
    }
  }
}

// ====== MFMA flash attention: block-shared K/V chunks via LDS ===============
// TA model (R2-R5 data): each global-load inst costs ~64 addr cycles/CU,
// regardless of width/caching -> minimize VMEM instructions per chunk-unit.
// 1024 blocks x 4 waves; wave w owns q-block qb = 4G+w (32 q rows); all 4
// waves iterate the SAME chunks c=0..4G+3. Per chunk the block stages
// K (2KB) + V (2KB) into LDS with 4 gld16 (one per wave, 1KB each) = 1 VMEM
// inst per chunk-unit (was 4-6). LDS uses fragment-linear layout (staging
// SOURCE is per-lane) so every fragment read is ds_read_b128 at lane*16 —
// conflict-free. Zero-shuffle P (R5, bit-exact) -> no P LDS. Double-buffered,
// 1 gld16 in flight, drained after ~300cy of compute. Group sequence G is a
// balanced permutation so any round-robin window of 4 blocks/CU has equal
// total chunks (work varies 16:1 and grid == capacity).
__global__ void __launch_bounds__(256, 6) k_attn(
    const unsigned short* __restrict__ QB16,
    const unsigned short* __restrict__ KB16,
    const unsigned short* __restrict__ VT16,
    float* __restrict__ OH) {
  __shared__ unsigned char kv[2][4096];   // [buf][Kt0 1K | Kt1 1K | Vh0 1K | Vh1 1K]
  const int wid = threadIdx.x >> 6;
  const int lane = threadIdx.x & 63;
  const int qL = lane & 15, quad = lane >> 4;
  const int bk = blockIdx.x;              // 1024
  const int combo = bk & 63;              // XCD-local K/V (combo%8 == bk%8)
  // G sequence {15,14,13,12, 0,1,2,3, 11,10,9,8, 4,5,6,7}: windows of 4
  // spaced 4 apart sum to 30 each -> per-CU chunk totals equalized.
  const int ii = bk >> 6, qd = ii >> 2, rr = ii & 3;
  const int G = (qd & 1) ? (rr + ((qd & 2) << 1)) : (15 - rr - ((qd & 2) << 1));
  const int qbw = 4 * G + wid;            // this wave's q-block
  const int cmax = 4 * G + 3;             // chunks staged per block
  const int b = combo >> 5, hh = combo & 31;
  const int q0 = qbw * 32;

  const unsigned short* QB = QB16 + (size_t)(b * 32 + hh) * SLEN * 32;
  const unsigned short* KB = KB16 + (size_t)(b * 32 + hh) * SLEN * 32;
  const unsigned short* VT = VT16 + (size_t)(b * 32 + hh) * 32 * SLEN;

  const short8v qf0 = *(const short8v*)(QB + (size_t)(q0 + qL) * 32 + quad * 8);
  const short8v qf1 = *(const short8v*)(QB + (size_t)(q0 + 16 + qL) * 32 + quad * 8);
  const f32x4 zz = {0.f, 0.f, 0.f, 0.f};
  f32x4 a00 = zz, a01 = zz, a10 = zz, a11 = zz;
  float l0 = 0.f, l1 = 0.f;

  // staging duty: w0 -> K tile0 (keys 32c+qL), w1 -> K tile1 (keys 32c+16+qL),
  // w2 -> V h0 (d=qL), w3 -> V h1 (d=16+qL). Lane's 16B source == exactly the
  // fragment reader lane (qL,quad) consumes -> LDS read is linear lane*16.
  const unsigned short* sbase = (wid < 2)
      ? KB + (size_t)(wid * 16 + qL) * 32 + quad * 8
      : VT + (size_t)((wid - 2) * 16 + qL) * 2048 + quad * 8;
  const int sstep = (wid < 2) ? 1024 : 32;  // shorts per chunk along source
  unsigned short* d0 = (unsigned short*)(&kv[0][0] + wid * 1024);
  unsigned short* d1 = (unsigned short*)(&kv[1][0] + wid * 1024);

  gld16(sbase, d0);                       // stage chunk 0 -> buf 0
  WVN(0);
  SB();

  #pragma unroll 1
  for (int c = 0; c <= cmax; ++c) {
    const unsigned char* kb = &kv[c & 1][0];
    if (c < cmax) gld16(sbase + (size_t)(c + 1) * sstep, (c & 1) ? d0 : d1);
    if (c <= qbw) {
      short8v kf0 = *(const short8v*)(kb + lane * 16);
      short8v kf1 = *(const short8v*)(kb + 1024 + lane * 16);
      short8v vf0 = *(const short8v*)(kb + 2048 + lane * 16);
      short8v vf1 = *(const short8v*)(kb + 3072 + lane * 16);
      if (c < qbw) {                      // full (unmasked) chunk
        f32x4 s00 = __builtin_amdgcn_mfma_f32_16x16x32_bf16(kf0, qf0, zz, 0, 0, 0);
        f32x4 s01 = __builtin_amdgcn_mfma_f32_16x16x32_bf16(kf1, qf0, zz, 0, 0, 0);
        f32x4 s10 = __builtin_amdgcn_mfma_f32_16x16x32_bf16(kf0, qf1, zz, 0, 0, 0);
        f32x4 s11 = __builtin_amdgcn_mfma_f32_16x16x32_bf16(kf1, qf1, zz, 0, 0, 0);
        float p00[4], p01[4], p10[4], p11[4];
        #pragma unroll
        for (int r = 0; r < 4; ++r) {
          p00[r] = __builtin_amdgcn_exp2f(s00[r]);
          p01[r] = __builtin_amdgcn_exp2f(s01[r]);
          p10[r] = __builtin_amdgcn_exp2f(s10[r]);
          p11[r] = __builtin_amdgcn_exp2f(s11[r]);
        }
        l0 += (p00[0] + p00[1] + p00[2] + p00[3]) + (p01[0] + p01[1] + p01[2] + p01[3]);
        l1 += (p10[0] + p10[1] + p10[2] + p10[3]) + (p11[0] + p11[1] + p11[2] + p11[3]);
        u32x4 up0 = {pk2(p00[0], p00[1]), pk2(p00[2], p00[3]),
                     pk2(p01[0], p01[1]), pk2(p01[2], p01[3])};
        u32x4 up1 = {pk2(p10[0], p10[1]), pk2(p10[2], p10[3]),
                     pk2(p11[0], p11[1]), pk2(p11[2], p11[3])};
        short8v pf0 = __builtin_bit_cast(short8v, up0);
        short8v pf1 = __builtin_bit_cast(short8v, up1);
        a00 = __builtin_amdgcn_mfma_f32_16x16x32_bf16(vf0, pf0, a00, 0, 0, 0);
        a01 = __builtin_amdgcn_mfma_f32_16x16x32_bf16(vf1, pf0, a01, 0, 0, 0);
        a10 = __builtin_amdgcn_mfma_f32_16x16x32_bf16(vf0, pf1, a10, 0, 0, 0);
        a11 = __builtin_amdgcn_mfma_f32_16x16x32_bf16(vf1, pf1, a11, 0, 0, 0);
      } else {                            // tail chunk (diagonal masks)
        f32x4 s00 = __builtin_amdgcn_mfma_f32_16x16x32_bf16(kf0, qf0, zz, 0, 0, 0);
        f32x4 s10 = __builtin_amdgcn_mfma_f32_16x16x32_bf16(kf0, qf1, zz, 0, 0, 0);
        f32x4 s11 = __builtin_amdgcn_mfma_f32_16x16x32_bf16(kf1, qf1, zz, 0, 0, 0);
        float p00[4], p10[4], p11[4];
        #pragma unroll
        for (int r = 0; r < 4; ++r) {
          bool v = (4 * quad + r) <= qL;  // same predicate for s00 and s11
          p00[r] = v ? __builtin_amdgcn_exp2f(s00[r]) : 0.f;
          p10[r] = __builtin_amdgcn_exp2f(s10[r]);   // always valid
          p11[r] = v ? __builtin_amdgcn_exp2f(s11[r]) : 0.f;
        }
        l0 += (p00[0] + p00[1] + p00[2] + p00[3]);
        l1 += (p10[0] + p10[1] + p10[2] + p10[3]) + (p11[0] + p11[1] + p11[2] + p11[3]);
        u32x4 up0 = {pk2(p00[0], p00[1]), pk2(p00[2], p00[3]), 0u, 0u};
        u32x4 up1 = {pk2(p10[0], p10[1]), pk2(p10[2], p10[3]),
                     pk2(p11[0], p11[1]), pk2(p11[2], p11[3])};
        short8v pf0 = __builtin_bit_cast(short8v, up0);
        short8v pf1 = __builtin_bit_cast(short8v, up1);
        a00 = __builtin_amdgcn_mfma_f32_16x16x32_bf16(vf0, pf0, a00, 0, 0, 0);
        a01 = __builtin_amdgcn_mfma_f32_16x16x32_bf16(vf1, pf0, a01, 0, 0, 0);
        a10 = __builtin_amdgcn_mfma_f32_16x16x32_bf16(vf0, pf1, a10, 0, 0, 0);
        a11 = __builtin_amdgcn_mfma_f32_16x16x32_bf16(vf1, pf1, a11, 0, 0, 0);
      }
    }
    if (c < cmax) WVN(0);                 // own gld16 landed (issued ~300cy ago)
    SB();                                 // reads of this buf done before next
  }                                       // iteration's stage overwrites it

  // epilogue: per-wave l reduction + OH write (no cross-wave combine)
  l0 += __shfl_xor(l0, 16); l0 += __shfl_xor(l0, 32);
  l1 += __shfl_xor(l1, 16); l1 += __shfl_xor(l1, 32);
  const float inv0 = 1.0f / l0, inv1 = 1.0f / l1;
  float* ob0 = OH + (((size_t)(b * SLEN + q0 + qL) * 32) + hh) * 32 + (quad << 2);
  float* ob1 = OH + (((size_t)(b * SLEN + q0 + 16 + qL) * 32) + hh) * 32 + (quad << 2);
  *(float4*)ob0        = (float4){a00[0] * inv0, a00[1] * inv0, a00[2] * inv0, a00[3] * inv0};
  *(float4*)(ob0 + 16) = (float4){a01[0] * inv0, a01[1] * inv0, a01[2] * inv0, a01[3] * inv0};
  *(float4*)ob1        = (float4){a10[0] * inv1, a10[1] * inv1, a10[2] * inv1, a10[3] * inv1};
  *(float4*)(ob1 + 16) = (float4){a11[0] * inv1, a11[1] * inv1, a11[2] * inv1, a11[3] * inv1};
}

// ================= k_tail: fused combine+xfeat + final ======================
// Block = 8 rows. Phase 1 (cxf): wave w reduces rows 2w,2w+1 -> XA/XS1 in LDS.
// Phase 2 (final): out[8][1024] = XA·A1T + XS1·A2T, A1T/A2T hoisted per-f.
__global__ void __launch_bounds__(256) k_tail(const float* __restrict__ OH,
    const float* __restrict__ dl, const float* __restrict__ FS,
    const float* __restrict__ FD, const float* __restrict__ A1T,
    const float* __restrict__ A2T, float* __restrict__ out) {
  __shared__ float XAs[8][16];
  __shared__ float XS1s[8][16];
  const int t = threadIdx.x;
  const int w = t >> 6, lane = t & 63;
  const int rbase = blockIdx.x * 8;           // 512 blocks
  {
    const float lam0 = dl[lane >> 3];
    const float lam1 = dl[8 + (lane >> 3)];
    const float* oh0 = OH + (size_t)(rbase + w * 2) * 1024;
    float4 y1a0 = *(const float4*)(oh0 + lane * 4);
    float4 y1b0 = *(const float4*)(oh0 + 256 + lane * 4);
    float4 y2a0 = *(const float4*)(oh0 + 512 + lane * 4);
    float4 y2b0 = *(const float4*)(oh0 + 768 + lane * 4);
    float4 y1a1 = *(const float4*)(oh0 + 1024 + lane * 4);
    float4 y1b1 = *(const float4*)(oh0 + 1280 + lane * 4);
    float4 y2a1 = *(const float4*)(oh0 + 1536 + lane * 4);
    float4 y2b1 = *(const float4*)(oh0 + 1792 + lane * 4);
    y2a0.x *= lam0; y2a0.y *= lam0; y2a0.z *= lam0; y2a0.w *= lam0;
    y2b0.x *= lam1; y2b0.y *= lam1; y2b0.z *= lam1; y2b0.w *= lam1;
    y2a1.x *= lam0; y2a1.y *= lam0; y2a1.z *= lam0; y2a1.w *= lam0;
    y2b1.x *= lam1; y2b1.y *= lam1; y2b1.z *= lam1; y2b1.w *= lam1;
    float acc0[16], acc1[16];
    #pragma unroll
    for (int f = 0; f < 16; ++f) {
      float4 sa = *(const float4*)(FS + f * 512 + lane * 4);
      float4 sb = *(const float4*)(FS + f * 512 + 256 + lane * 4);
      float4 da = *(const float4*)(FD + f * 512 + lane * 4);
      float4 db = *(const float4*)(FD + f * 512 + 256 + lane * 4);
      acc0[f] = dot4(y1a0, sa) + dot4(y1b0, sb) + dot4(y2a0, da) + dot4(y2b0, db);
      acc1[f] = dot4(y1a1, sa) + dot4(y1b1, sb) + dot4(y2a1, da) + dot4(y2b1, db);
    }
    #pragma unroll
    for (int f = 0; f < 16; ++f) {
      #pragma unroll
      for (int off = 32; off >= 1; off >>= 1) {
        acc0[f] += __shfl_xor(acc0[f], off);
        acc1[f] += __shfl_xor(acc1[f], off);
      }
    }
    if (lane == 0) {
      #pragma unroll
      for (int f = 0; f < 16; ++f) {
        float xf = acc0[f];
        float xs = 1.0f / (1.0f + expf(-5.0f * xf));
        XAs[w * 2][f] = xf * xs;
        XS1s[w * 2][f] = 1.0f - xs;
        float xg = acc1[f];
        float xt = 1.0f / (1.0f + expf(-5.0f * xg));
        XAs[w * 2 + 1][f] = xg * xt;
        XS1s[w * 2 + 1][f] = 1.0f - xt;
      }
    }
  }
  __syncthreads();
  {
    float4 acc[8];
    #pragma unroll
    for (int rr = 0; rr < 8; ++rr) acc[rr] = (float4){0.f, 0.f, 0.f, 0.f};
    #pragma unroll
    for (int f = 0; f < 16; ++f) {
      float4 a1 = *(const float4*)(A1T + f * 1024 + t * 4);
      float4 a2 = *(const float4*)(A2T + f * 1024 + t * 4);
      #pragma unroll
      for (int rr = 0; rr < 8; ++rr) {
        float xa = XAs[rr][f], x1 = XS1s[rr][f];
        acc[rr].x = fmaf(xa, a1.x, fmaf(x1, a2.x, acc[rr].x));
        acc[rr].y = fmaf(xa, a1.y, fmaf(x1, a2.y, acc[rr].y));
        acc[rr].z = fmaf(xa, a1.z, fmaf(x1, a2.z, acc[rr].z));
        acc[rr].w = fmaf(xa, a1.w, fmaf(x1, a2.w, acc[rr].w));
      }
    }
    #pragma unroll
    for (int rr = 0; rr < 8; ++rr)
      *(float4*)(out + (size_t)(rbase + rr) * 1024 + t * 4) = acc[rr];
  }
}

extern "C" void kernel_launch(void* const* d_in, const int* in_sizes, int n_in,
                              void* d_out, int out_size, void* d_ws, size_t ws_size,
                              hipStream_t stream) {
  const float* x      = (const float*)d_in[0];
  const float* w_qkv  = (const float*)d_in[1];
  const float* feats  = (const float*)d_in[2];
  const float* protos = (const float*)d_in[3];
  const float* theta  = (const float*)d_in[4];
  const float* alpha  = (const float*)d_in[5];
  const float* beta   = (const float*)d_in[6];
  const float* q_gain = (const float*)d_in[7];
  const float* dlam   = (const float*)d_in[8];
  float* out = (float*)d_out;
  float* ws  = (float*)d_ws;

  // workspace layout
  float* QKV = ws;                    // 12,582,912
  float* OH  = QKV + 12582912;        // 4,194,304
  float* COS = OH  + 4194304;         // 65,536
  float* SIN = COS + 65536;           // 65,536
  float* PT  = SIN + 65536;           // 1,048,576
  float* A1T = PT  + 1048576;         // 16,384
  float* A2T = A1T + 16384;           // 16,384
  float* XA  = A2T + 16384;           // 65,536 (unused, kept for layout)
  float* XS1 = XA  + 65536;           // 65,536 (unused)
  unsigned short* QB16 = (unsigned short*)(XS1 + 65536);  // 4,194,304
  unsigned short* KB16 = QB16 + 4194304;                  // 4,194,304
  unsigned short* VT16 = KB16 + 4194304;                  // 4,194,304
  unsigned short* Wb   = VT16 + 4194304;                  // 3,145,728
  unsigned short* Xhi  = Wb   + 3145728;                  // 4,194,304
  unsigned short* Xlo  = Xhi  + 4194304;                  // 4,194,304
  float* FS = (float*)(Xlo + 4194304);                    // 8,192
  float* FD = FS + 8192;                                  // 8,192

  k_prep<<<8480, 256, 0, stream>>>(w_qkv, protos, x, feats, Wb, PT,
                                   Xhi, Xlo, COS, SIN, FS, FD);
  k_gemm4<<<256, 512, 0, stream>>>(Xhi, Xlo, Wb, QKV);
  k_mid<<<10496, 256, 0, stream>>>(QKV, COS, SIN, q_gain, QB16, KB16, VT16,
                                   PT, feats, theta, alpha, beta, A1T, A2T);
  k_attn<<<1024, 256, 0, stream>>>(QB16, KB16, VT16, OH);
  k_tail<<<512, 256, 0, stream>>>(OH, dlam, FS, FD, A1T, A2T, out);
}

// Round 8
// 219.544 us; speedup vs baseline: 1.3315x; 1.0025x over previous
//
#include <hip/hip_runtime.h>
#include <hip/hip_bf16.h>
#include <math.h>

// Problem constants
#define DIM   1024
#define NHEAD 16
#define SLEN  2048
#define BATCH 2
#define NROWS (BATCH*SLEN)   // 4096
#define QKV_N 3072

typedef __attribute__((ext_vector_type(8))) short short8v;
typedef __attribute__((ext_vector_type(4))) short short4v;
typedef __attribute__((ext_vector_type(4))) float f32x4;
typedef __attribute__((ext_vector_type(4))) unsigned int u32x4;

// RNE float->bf16 bit tricks (valid for finite, non-overflowing inputs —
// identical result to __float2bfloat16 / jnp astype for our value ranges)
__device__ __forceinline__ unsigned short rne16(float f) {
  unsigned u = __float_as_uint(f);
  u += 0x7FFFu + ((u >> 16) & 1u);
  return (unsigned short)(u >> 16);
}
__device__ __forceinline__ float rnef(float f) {
  unsigned u = __float_as_uint(f);
  u += 0x7FFFu + ((u >> 16) & 1u);
  return __uint_as_float(u & 0xFFFF0000u);
}
// pack two floats as bf16 pair (RNE), low = a, high = b.
// v_cvt_pk_bf16_f32 is RNE on gfx950 -> bit-identical to the bit-trick pk2.
__device__ __forceinline__ unsigned pk2(float a, float b) {
  unsigned r;
  asm("v_cvt_pk_bf16_f32 %0, %1, %2" : "=v"(r) : "v"(a), "v"(b));
  return r;
}

// async global->LDS, 16 bytes per lane; LDS dest = wave-uniform base + lane*16
__device__ __forceinline__ void gld16(const unsigned short* g, unsigned short* l) {
  __builtin_amdgcn_global_load_lds(
      (const __attribute__((address_space(1))) unsigned int*)g,
      (__attribute__((address_space(3))) unsigned int*)l, 16, 0, 0);
}

// ================= k_prep: all independent input transforms =================
// blocks [0,3072)      ternary(w_qkv) -> bf16 Wb      (float4/lane)
// blocks [3072,4096)   ternary(protos) -> fp32 PT     (float4/lane)
// blocks [4096,8192)   xsplit (x -> Xhi,Xlo)
// blocks [8192,8448)   rope tables
// blocks [8448,8480)   feature split FS/FD
// Ternary reduction tree is a BIT-EXACT replica of the old 64-lane tree:
// old lane = 4*j + e (j = lane-group index, e = elem); old offsets {32,16,8,4}
// == per-component shfl offsets {8,4,2,1}; old offsets {2,1} == final
// (a0+a2)+(a1+a3). Same values, same association order -> same scale bits.
__global__ void __launch_bounds__(256) k_prep(
    const float* __restrict__ w_qkv, const float* __restrict__ protos,
    const float* __restrict__ x, const float* __restrict__ F,
    unsigned short* __restrict__ Wb, float* __restrict__ PT,
    unsigned short* __restrict__ Xhi, unsigned short* __restrict__ Xlo,
    float* __restrict__ cosT, float* __restrict__ sinT,
    float* __restrict__ FS, float* __restrict__ FD) {
  const int blk = blockIdx.x, tid = threadIdx.x;
  if (blk < 4096) {                        // ternary (w_qkv or protos)
    const bool isw = (blk < 3072);
    const int idx = (isw ? blk * 256 + tid : (blk - 3072) * 256 + tid) * 4;
    const float* src = isw ? w_qkv : protos;
    float4 v = *(const float4*)(src + idx);
    float b0 = rnef(v.x), b1 = rnef(v.y), b2 = rnef(v.z), b3 = rnef(v.w);
    float a0 = fabsf(b0), a1 = fabsf(b1), a2 = fabsf(b2), a3 = fabsf(b3);
    #pragma unroll
    for (int off = 8; off >= 1; off >>= 1) {
      a0 += __shfl_xor(a0, off); a1 += __shfl_xor(a1, off);
      a2 += __shfl_xor(a2, off); a3 += __shfl_xor(a3, off);
    }
    float s = (a0 + a2) + (a1 + a3);
    float scale = fmaxf(rnef(s * (1.0f / 64.0f)), 1e-8f);
    auto tern = [&](float wb) -> float {
      float q = fminf(1.0f, fmaxf(-1.0f, rintf(rnef(wb / scale))));
      float deq = rnef(q * scale);
      float d = rnef(deq - wb);
      return wb + d;
    };
    if (isw) {
      short4v o;
      o[0] = (short)rne16(tern(b0)); o[1] = (short)rne16(tern(b1));
      o[2] = (short)rne16(tern(b2)); o[3] = (short)rne16(tern(b3));
      *(short4v*)(Wb + idx) = o;
    } else {
      float4 o = {rnef(tern(b0)), rnef(tern(b1)), rnef(tern(b2)), rnef(tern(b3))};
      *(float4*)(PT + idx) = o;
    }
  } else if (blk < 8192) {                 // xsplit
    int idx = (blk - 4096) * 256 + tid;
    float4 v = *(const float4*)(x + (size_t)idx * 4);
    short4v hi, lo;
    float h0 = rnef(v.x); hi[0] = (short)rne16(v.x); lo[0] = (short)rne16(v.x - h0);
    float h1 = rnef(v.y); hi[1] = (short)rne16(v.y); lo[1] = (short)rne16(v.y - h1);
    float h2 = rnef(v.z); hi[2] = (short)rne16(v.z); lo[2] = (short)rne16(v.z - h2);
    float h3 = rnef(v.w); hi[3] = (short)rne16(v.w); lo[3] = (short)rne16(v.w - h3);
    *(short4v*)(Xhi + (size_t)idx * 4) = hi;
    *(short4v*)(Xlo + (size_t)idx * 4) = lo;
  } else if (blk < 8448) {                 // rope tables
    int idx = (blk - 8192) * 256 + tid;    // 65536
    int s = idx >> 5, j = idx & 31;
    double inv  = 1.0 / pow(10000.0, (double)(2 * j) / 64.0);
    double ramp = ((double)(2 * j) / 64.0 - 0.25) / 0.75;
    ramp = ramp < 0.0 ? 0.0 : (ramp > 1.0 ? 1.0 : ramp);
    inv /= (ramp * 3.0 + 1.0);
    float freq = (float)s * (float)inv;
    cosT[idx] = (float)cos((double)freq);
    sinT[idx] = (float)sin((double)freq);
  } else {                                 // fsplit
    int idx = (blk - 8448) * 256 + tid;    // 8192
    int f = idx >> 9, hd = idx & 511;
    int h = hd >> 5, d = hd & 31;
    float a = F[f * 1024 + h * 64 + d];
    float b = F[f * 1024 + h * 64 + 32 + d];
    FS[idx] = a + b;
    FD[idx] = b - a;
  }
}

// ===== 256x192 shared-B 4-phase bf16 MFMA GEMM + fused normrope/vtrans ======
// (Xhi+Xlo)·Wb^T over K=1024, tile 256x192; grid 16x16 = 256 blocks.
// K-loop identical to R6/R7 (B staged once per kc, 4 phases, counted vmcnt).
// EPILOGUE (new): QKV is NEVER materialized. BN=192 = 3 complete 64-dim
// head-chunks and BM=256 = complete sequence rows, so rmsnorm (per row x
// 64-chunk), rope (pairs d,d+32), q_gain, and the V chunk-permuted transpose
// all close within the block. Per qm half: stage acc to LDS f32 [128][196]
// (100KB <= 112KB, stride 196 -> stage writes & V column reads are 2-way
// aliased = free), then 16-lane groups run the EXACT R7 normrope code on it
// (same shfl tree {8,4,2,1}, same (s0+s2)+(s1+s3), same rope/FOLD math, same
// store layout) -> Q/K/V outputs bit-identical to R7. Saves 50MB write +
// 48MB read of QKV traffic and the separate k_mid sections.
#define FEN() asm volatile("" ::: "memory")
#define SB()  do { FEN(); __builtin_amdgcn_s_barrier(); FEN(); } while (0)
#define WL()  do { asm volatile("s_waitcnt lgkmcnt(0)" ::: "memory"); \
                   __builtin_amdgcn_sched_barrier(0); } while (0)
#define WVN(n) asm volatile("s_waitcnt vmcnt(" #n ")" ::: "memory")

__global__ void __launch_bounds__(512, 2) k_gemm4(
    const unsigned short* __restrict__ Xhi, const unsigned short* __restrict__ Xlo,
    const unsigned short* __restrict__ Wb,
    const float* __restrict__ cosT, const float* __restrict__ sinT,
    const float* __restrict__ q_gain,
    unsigned short* __restrict__ QB16, unsigned short* __restrict__ KB16,
    unsigned short* __restrict__ VT16) {
  __shared__ unsigned char lds[114688];
  const int t = threadIdx.x;
  const int lane = t & 63;
  const int qL = lane & 15, quad = lane >> 4;
  const int wid = t >> 6;
  const int wm = wid >> 2, wn = wid & 3;   // 2M x 4N waves; per-wave 128x48
  // XCD-aware swizzle: 256 % 8 == 0 -> bijective
  const int bid = blockIdx.x;
  const int swz = (bid & 7) * 32 + (bid >> 3);
  const int by = swz >> 4, bx = swz & 15;
  const int bm = by * 256, bn = bx * 192;
  // swizzled ds_read inner offset (st_16x32 within 1024B subtile)
  const int inner = qL * 64 + ((quad * 16) ^ ((qL & 8) << 2));
  // staging decode: linear dest L -> logical (row, col) via involution P
  int rj[3], cj[3];
  #pragma unroll
  for (int j = 0; j < 3; ++j) {
    int L = j * 8192 + t * 16;
    int Lp = L ^ (((L >> 9) & 1) << 5);
    int st = Lp >> 10;
    rj[j] = (st >> 1) * 16 + ((Lp >> 6) & 15);
    cj[j] = (st & 1) * 32 + ((Lp & 63) >> 1);
  }
  unsigned char* AHI = lds;                 // 2 halves x 16K
  unsigned char* ALO = lds + 32768;         // 2 halves x 16K
  unsigned char* BB  = lds + 65536;         // 2 bufs x 24K

  // stage A half-tile (128 rows interleaved as wm-blocks) of panel at kc
  auto STA = [&](const unsigned short* __restrict__ pan, unsigned char* reg,
                 int kc, int h) {
    unsigned char* lb = reg + h * 16384 + (t >> 6) * 1024;
    #pragma unroll
    for (int j = 0; j < 2; ++j) {
      int rr = bm + ((rj[j] >> 6) * 128) + h * 64 + (rj[j] & 63);
      gld16(pan + (size_t)rr * 1024 + kc + cj[j], (unsigned short*)(lb + j * 8192));
    }
  };
  // stage whole B tile (192 rows) of kc into buf
  auto STB = [&](int kc, int buf) {
    unsigned char* lb = BB + buf * 24576 + (t >> 6) * 1024;
    #pragma unroll
    for (int j = 0; j < 3; ++j)
      gld16(Wb + (size_t)(bn + rj[j]) * 1024 + kc + cj[j],
            (unsigned short*)(lb + j * 8192));
  };

  short8v aF[4][2], bF[3][2];
  f32x4 acc[2][4][3];
  const f32x4 zz = {0.f, 0.f, 0.f, 0.f};
  #pragma unroll
  for (int q_ = 0; q_ < 2; ++q_)
    #pragma unroll
    for (int m_ = 0; m_ < 4; ++m_)
      #pragma unroll
      for (int n_ = 0; n_ < 3; ++n_) acc[q_][m_][n_] = zz;

  auto RA = [&](unsigned char* reg, int qm_) {
    #pragma unroll
    for (int mi = 0; mi < 4; ++mi)
      #pragma unroll
      for (int ks = 0; ks < 2; ++ks)
        aF[mi][ks] = *(const short8v*)(reg + qm_ * 16384 +
                                       ((((wm * 4 + mi) << 1) + ks) << 10) + inner);
  };
  auto RB = [&](int buf) {
    #pragma unroll
    for (int ni = 0; ni < 3; ++ni)
      #pragma unroll
      for (int ks = 0; ks < 2; ++ks)
        bF[ni][ks] = *(const short8v*)(BB + buf * 24576 +
                                       ((((wn * 3 + ni) << 1) + ks) << 10) + inner);
  };
  auto MM = [&](int qm_) {
    __builtin_amdgcn_s_setprio(1);
    #pragma unroll
    for (int ks = 0; ks < 2; ++ks)       // ks outer: dependent pairs 12 apart
      #pragma unroll
      for (int mi = 0; mi < 4; ++mi)
        #pragma unroll
        for (int ni = 0; ni < 3; ++ni)
          acc[qm_][mi][ni] = __builtin_amdgcn_mfma_f32_16x16x32_bf16(
              aF[mi][ks], bF[ni][ks], acc[qm_][mi][ni], 0, 0, 0);
    __builtin_amdgcn_s_setprio(0);
  };

  // prologue: B(0) + Ahi halves + Alo-h0 (9 units); leave newest 4 in flight
  STB(0, 0); STA(Xhi, AHI, 0, 0); STA(Xhi, AHI, 0, 1); STA(Xlo, ALO, 0, 0);
  WVN(4);
  SB();

  #pragma unroll 1
  for (int i = 0; i < 16; ++i) {
    const int kc = i * 64, kn = kc + 64;
    const bool nl = (i < 15);
    const int cb = i & 1, nb = cb ^ 1;
    // ph1: (qm0, hi) — read B once for the whole iteration
    RA(AHI, 0); RB(cb); STA(Xlo, ALO, kc, 1);
    SB(); WL(); MM(0);
    WVN(4);                                   // Ahi-h1(i) landed
    SB();
    // ph2: (qm1, hi)
    RA(AHI, 1);
    if (nl) { STB(kn, nb); STA(Xhi, AHI, kn, 0); }
    SB(); WL(); MM(1);
    if (nl) { WVN(7); } else { WVN(2); }      // Alo-h0(i) landed
    SB();
    // ph3: (qm0, lo)
    RA(ALO, 0);
    if (nl) STA(Xhi, AHI, kn, 1);
    SB(); WL(); MM(0);
    if (nl) { WVN(7); } else { WVN(0); }      // Alo-h1(i) landed
    SB();
    // ph4: (qm1, lo)
    RA(ALO, 1);
    if (nl) STA(Xlo, ALO, kn, 0);
    SB(); WL(); MM(1);
    if (nl) WVN(4);                           // B(i+1), Ahi-h0(i+1) landed
    SB();
  }

  // ===== fused epilogue: per qm half, LDS-stage then normrope/vtrans =====
  float* S = (float*)lds;                  // [128][196] f32
  const int bb = bm >> 11;                 // batch index (256 | 2048)
  const int lg = t & 15;                   // lane within 16-group
  const int g16 = t >> 4;                  // group id 0..31
  const int gch0 = bn >> 6;                // first global 64-col chunk (0..47)

  auto EPI = [&](const f32x4 (&ap)[4][3], int p) {
    // stage this qm-half's acc into S (2-way bank alias = free)
    #pragma unroll
    for (int mi = 0; mi < 4; ++mi)
      #pragma unroll
      for (int ni = 0; ni < 3; ++ni) {
        const int sr = wm * 64 + mi * 16 + quad * 4;
        const int colL = wn * 48 + ni * 16 + qL;
        #pragma unroll
        for (int r = 0; r < 4; ++r)
          S[(sr + r) * 196 + colL] = ap[mi][ni][r];
      }
    SB();
    // q/k chunks: rmsnorm + rope + gain (exact R7 normrope math, bit-exact)
    #pragma unroll 1
    for (int u = g16; u < 384; u += 32) {
      const int chunk = u >> 7, sr = u & 127;
      const int gch = gch0 + chunk;
      if (gch < 32) {
        float4 xv = *(const float4*)&S[sr * 196 + chunk * 64 + lg * 4];
        float s0 = xv.x * xv.x, s1 = xv.y * xv.y;
        float s2 = xv.z * xv.z, s3 = xv.w * xv.w;
        #pragma unroll
        for (int off = 8; off >= 1; off >>= 1) {
          s0 += __shfl_xor(s0, off); s1 += __shfl_xor(s1, off);
          s2 += __shfl_xor(s2, off); s3 += __shfl_xor(s3, off);
        }
        float ss = (s0 + s2) + (s1 + s3);
        float inv = rsqrtf(ss * (1.0f / 64.0f) + 1e-5f);
        float xn0 = xv.x * inv, xn1 = xv.y * inv;
        float xn2 = xv.z * inv, xn3 = xv.w * inv;
        const int s_glob = bm + ((sr >> 6) << 7) + p * 64 + (sr & 63);
        const int srow = s_glob & (SLEN - 1);
        const int j4 = (lg & 7) * 4;
        float4 c4 = *(const float4*)(cosT + srow * 32 + j4);
        float4 n4 = *(const float4*)(sinT + srow * 32 + j4);
        float ot0 = __shfl_xor(xn0, 8), ot1 = __shfl_xor(xn1, 8);
        float ot2 = __shfl_xor(xn2, 8), ot3 = __shfl_xor(xn3, 8);
        const bool hi = (lg & 8) != 0;
        float o0 = hi ? fmaf(xn0, c4.x, -ot0 * n4.x) : fmaf(xn0, c4.x, ot0 * n4.x);
        float o1 = hi ? fmaf(xn1, c4.y, -ot1 * n4.y) : fmaf(xn1, c4.y, ot1 * n4.y);
        float o2 = hi ? fmaf(xn2, c4.z, -ot2 * n4.z) : fmaf(xn2, c4.z, ot2 * n4.z);
        float o3 = hi ? fmaf(xn3, c4.w, -ot3 * n4.w) : fmaf(xn3, c4.w, ot3 * n4.w);
        const int h = gch & 15;
        const int hh = h + (hi ? 16 : 0);
        size_t addr = (((size_t)(bb * 32 + hh) * SLEN) + srow) * 32 + j4;
        short4v o;
        if (gch < 16) {
          const float FOLD = 0.17677669529663687f * 1.4426950408889634f;
          float gq = q_gain[h];
          o[0] = (short)rne16(o0 * gq * FOLD); o[1] = (short)rne16(o1 * gq * FOLD);
          o[2] = (short)rne16(o2 * gq * FOLD); o[3] = (short)rne16(o3 * gq * FOLD);
          *(short4v*)(QB16 + addr) = o;
        } else {
          o[0] = (short)rne16(o0); o[1] = (short)rne16(o1);
          o[2] = (short)rne16(o2); o[3] = (short)rne16(o3);
          *(short4v*)(KB16 + addr) = o;
        }
      }
    }
    // v chunks: chunk-permuted transpose store (same layout as R7 vtrans)
    const int wid8 = t >> 6;
    const int cl = t & 63;
    #pragma unroll 1
    for (int c3 = 0; c3 < 3; ++c3) {
      const int gch = gch0 + c3;
      if (gch >= 32) {
        const int hv = gch - 32;
        const int hh = (cl >= 32) ? hv + 16 : hv;
        const int dpl = cl & 31;
        unsigned short* vrow = VT16 + (((size_t)(bb * 32 + hh) * 32) + dpl) * SLEN;
        #pragma unroll
        for (int k4 = 0; k4 < 4; ++k4) {
          const int sr = wid8 * 16 + k4 * 4;
          const int s_glob = bm + ((sr >> 6) << 7) + p * 64 + (sr & 63);
          const int srow = s_glob & (SLEN - 1);
          const int c32 = srow & ~31, kc = srow & 31;
          const int p0 = 8 * ((kc & 15) >> 2) + 4 * (kc >> 4);
          short4v o;
          o[0] = (short)rne16(S[(sr + 0) * 196 + c3 * 64 + cl]);
          o[1] = (short)rne16(S[(sr + 1) * 196 + c3 * 64 + cl]);
          o[2] = (short)rne16(S[(sr + 2) * 196 + c3 * 64 + cl]);
          o[3] = (short)rne16(S[(sr + 3) * 196 + c3 * 64 + cl]);
          *(short4v*)(vrow + c32 + p0) = o;
        }
      }
    }
    SB();                                  // reads done before next stage
  };
  EPI(acc[0], 0);                          // literal acc index (rule #20)
  EPI(acc[1], 1);
}

// ================= k_mid: prototype projection only =========================
// 256 blocks x 256 thr; unit o = blk*4 + wave. (normrope/vtrans now fused
// into k_gemm4's epilogue.)
__device__ __forceinline__ float dot4(float4 a, float4 b) {
  return fmaf(a.x, b.x, fmaf(a.y, b.y, fmaf(a.z, b.z, a.w * b.w)));
}
__global__ void __launch_bounds__(256) k_mid(
    const float* __restrict__ PT, const float* __restrict__ F,
    const float* __restrict__ thp, const float* __restrict__ alp,
    const float* __restrict__ bep,
    float* __restrict__ A1T, float* __restrict__ A2T) {
  const int t = threadIdx.x;
  const int w = t >> 6, lane = t & 63;
  const int o = blockIdx.x * 4 + w;
  const float* pr = PT + (size_t)o * 1024;
  float4 p0 = *(const float4*)(pr + lane * 4);
  float4 p1 = *(const float4*)(pr + 256 + lane * 4);
  float4 p2 = *(const float4*)(pr + 512 + lane * 4);
  float4 p3 = *(const float4*)(pr + 768 + lane * 4);
  float acc[16];
  #pragma unroll
  for (int f = 0; f < 16; ++f) {
    const float* fr = F + (size_t)f * 1024;
    float4 f0 = *(const float4*)(fr + lane * 4);
    float4 f1 = *(const float4*)(fr + 256 + lane * 4);
    float4 f2 = *(const float4*)(fr + 512 + lane * 4);
    float4 f3 = *(const float4*)(fr + 768 + lane * 4);
    acc[f] = dot4(p0, f0) + dot4(p1, f1) + dot4(p2, f2) + dot4(p3, f3);
  }
  #pragma unroll
  for (int f = 0; f < 16; ++f) {
    #pragma unroll
    for (int off = 32; off >= 1; off >>= 1) acc[f] += __shfl_xor(acc[f], off);
  }
  if (lane == 0) {
    float th = fabsf(*thp), al = fabsf(*alp), be = fabsf(*bep);
    #pragma unroll
    for (int f = 0; f < 16; ++f) {
      float pf = acc[f];
      float ps = 1.0f / (1.0f + expf(-5.0f * pf));
      float pa = pf * ps;
      A1T[f * 1024 + o] = th * pa - al * (1.0f - ps);
      A2T[f * 1024 + o] = -be * pa;
    }
  }
}

// ====== MFMA flash attention: block-shared K/V chunks via LDS ===============
// TA model (R2-R5 data): each global-load inst costs ~64 addr cycles/CU,
// regardless of width/caching -> minimize VMEM instructions per chunk-unit.
// 1024 blocks x 4 waves; wave w owns q-block qb = 4G+w (32 q rows); all 4
// waves iterate the SAME chunks c=0..4G+3. Per chunk the block stages
// K (2KB) + V (2KB) into LDS with 4 gld16 (one per wave, 1KB each) = 1 VMEM
// inst per chunk-unit (was 4-6). LDS uses fragment-linear layout (staging
// SOURCE is per-lane) so every fragment read is ds_read_b128 at lane*16 —
// conflict-free. Zero-shuffle P (R5, bit-exact) -> no P LDS. Double-buffered,
// 1 gld16 in flight, drained after ~300cy of compute. Group sequence G is a
// balanced permutation so any round-robin window of 4 blocks/CU has equal
// total chunks (work varies 16:1 and grid == capacity).
__global__ void __launch_bounds__(256, 6) k_attn(
    const unsigned short* __restrict__ QB16,
    const unsigned short* __restrict__ KB16,
    const unsigned short* __restrict__ VT16,
    float* __restrict__ OH) {
  __shared__ unsigned char kv[2][4096];   // [buf][Kt0 1K | Kt1 1K | Vh0 1K | Vh1 1K]
  const int wid = threadIdx.x >> 6;
  const int lane = threadIdx.x & 63;
  const int qL = lane & 15, quad = lane >> 4;
  const int bk = blockIdx.x;              // 1024
  const int combo = bk & 63;              // XCD-local K/V (combo%8 == bk%8)
  // G sequence {15,14,13,12, 0,1,2,3, 11,10,9,8, 4,5,6,7}: windows of 4
  // spaced 4 apart sum to 30 each -> per-CU chunk totals equalized.
  const int ii = bk >> 6, qd = ii >> 2, rr = ii & 3;
  const int G = (qd & 1) ? (rr + ((qd & 2) << 1)) : (15 - rr - ((qd & 2) << 1));
  const int qbw = 4 * G + wid;            // this wave's q-block
  const int cmax = 4 * G + 3;             // chunks staged per block
  const int b = combo >> 5, hh = combo & 31;
  const int q0 = qbw * 32;

  const unsigned short* QB = QB16 + (size_t)(b * 32 + hh) * SLEN * 32;
  const unsigned short* KB = KB16 + (size_t)(b * 32 + hh) * SLEN * 32;
  const unsigned short* VT = VT16 + (size_t)(b * 32 + hh) * 32 * SLEN;

  const short8v qf0 = *(const short8v*)(QB + (size_t)(q0 + qL) * 32 + quad * 8);
  const short8v qf1 = *(const short8v*)(QB + (size_t)(q0 + 16 + qL) * 32 + quad * 8);
  const f32x4 zz = {0.f, 0.f, 0.f, 0.f};
  f32x4 a00 = zz, a01 = zz, a10 = zz, a11 = zz;
  float l0 = 0.f, l1 = 0.f;

  // staging duty: w0 -> K tile0 (keys 32c+qL), w1 -> K tile1 (keys 32c+16+qL),
  // w2 -> V h0 (d=qL), w3 -> V h1 (d=16+qL). Lane's 16B source == exactly the
  // fragment reader lane (qL,quad) consumes -> LDS read is linear lane*16.
  const unsigned short* sbase = (wid < 2)
      ? KB + (size_t)(wid * 16 + qL) * 32 + quad * 8
      : VT + (size_t)((wid - 2) * 16 + qL) * 2048 + quad * 8;
  const int sstep = (wid < 2) ? 1024 : 32;  // shorts per chunk along source
  unsigned short* d0 = (unsigned short*)(&kv[0][0] + wid * 1024);
  unsigned short* d1 = (unsigned short*)(&kv[1][0] + wid * 1024);

  gld16(sbase, d0);                       // stage chunk 0 -> buf 0
  WVN(0);
  SB();

  #pragma unroll 1
  for (int c = 0; c <= cmax; ++c) {
    const unsigned char* kb = &kv[c & 1][0];
    if (c < cmax) gld16(sbase + (size_t)(c + 1) * sstep, (c & 1) ? d0 : d1);
    if (c <= qbw) {
      short8v kf0 = *(const short8v*)(kb + lane * 16);
      short8v kf1 = *(const short8v*)(kb + 1024 + lane * 16);
      short8v vf0 = *(const short8v*)(kb + 2048 + lane * 16);
      short8v vf1 = *(const short8v*)(kb + 3072 + lane * 16);
      if (c < qbw) {                      // full (unmasked) chunk
        f32x4 s00 = __builtin_amdgcn_mfma_f32_16x16x32_bf16(kf0, qf0, zz, 0, 0, 0);
        f32x4 s01 = __builtin_amdgcn_mfma_f32_16x16x32_bf16(kf1, qf0, zz, 0, 0, 0);
        f32x4 s10 = __builtin_amdgcn_mfma_f32_16x16x32_bf16(kf0, qf1, zz, 0, 0, 0);
        f32x4 s11 = __builtin_amdgcn_mfma_f32_16x16x32_bf16(kf1, qf1, zz, 0, 0, 0);
        float p00[4], p01[4], p10[4], p11[4];
        #pragma unroll
        for (int r = 0; r < 4; ++r) {
          p00[r] = __builtin_amdgcn_exp2f(s00[r]);
          p01[r] = __builtin_amdgcn_exp2f(s01[r]);
          p10[r] = __builtin_amdgcn_exp2f(s10[r]);
          p11[r] = __builtin_amdgcn_exp2f(s11[r]);
        }
        l0 += (p00[0] + p00[1] + p00[2] + p00[3]) + (p01[0] + p01[1] + p01[2] + p01[3]);
        l1 += (p10[0] + p10[1] + p10[2] + p10[3]) + (p11[0] + p11[1] + p11[2] + p11[3]);
        u32x4 up0 = {pk2(p00[0], p00[1]), pk2(p00[2], p00[3]),
                     pk2(p01[0], p01[1]), pk2(p01[2], p01[3])};
        u32x4 up1 = {pk2(p10[0], p10[1]), pk2(p10[2], p10[3]),
                     pk2(p11[0], p11[1]), pk2(p11[2], p11[3])};
        short8v pf0 = __builtin_bit_cast(short8v, up0);
        short8v pf1 = __builtin_bit_cast(short8v, up1);
        a00 = __builtin_amdgcn_mfma_f32_16x16x32_bf16(vf0, pf0, a00, 0, 0, 0);
        a01 = __builtin_amdgcn_mfma_f32_16x16x32_bf16(vf1, pf0, a01, 0, 0, 0);
        a10 = __builtin_amdgcn_mfma_f32_16x16x32_bf16(vf0, pf1, a10, 0, 0, 0);
        a11 = __builtin_amdgcn_mfma_f32_16x16x32_bf16(vf1, pf1, a11, 0, 0, 0);
      } else {                            // tail chunk (diagonal masks)
        f32x4 s00 = __builtin_amdgcn_mfma_f32_16x16x32_bf16(kf0, qf0, zz, 0, 0, 0);
        f32x4 s10 = __builtin_amdgcn_mfma_f32_16x16x32_bf16(kf0, qf1, zz, 0, 0, 0);
        f32x4 s11 = __builtin_amdgcn_mfma_f32_16x16x32_bf16(kf1, qf1, zz, 0, 0, 0);
        float p00[4], p10[4], p11[4];
        #pragma unroll
        for (int r = 0; r < 4; ++r) {
          bool v = (4 * quad + r) <= qL;  // same predicate for s00 and s11
          p00[r] = v ? __builtin_amdgcn_exp2f(s00[r]) : 0.f;
          p10[r] = __builtin_amdgcn_exp2f(s10[r]);   // always valid
          p11[r] = v ? __builtin_amdgcn_exp2f(s11[r]) : 0.f;
        }
        l0 += (p00[0] + p00[1] + p00[2] + p00[3]);
        l1 += (p10[0] + p10[1] + p10[2] + p10[3]) + (p11[0] + p11[1] + p11[2] + p11[3]);
        u32x4 up0 = {pk2(p00[0], p00[1]), pk2(p00[2], p00[3]), 0u, 0u};
        u32x4 up1 = {pk2(p10[0], p10[1]), pk2(p10[2], p10[3]),
                     pk2(p11[0], p11[1]), pk2(p11[2], p11[3])};
        short8v pf0 = __builtin_bit_cast(short8v, up0);
        short8v pf1 = __builtin_bit_cast(short8v, up1);
        a00 = __builtin_amdgcn_mfma_f32_16x16x32_bf16(vf0, pf0, a00, 0, 0, 0);
        a01 = __builtin_amdgcn_mfma_f32_16x16x32_bf16(vf1, pf0, a01, 0, 0, 0);
        a10 = __builtin_amdgcn_mfma_f32_16x16x32_bf16(vf0, pf1, a10, 0, 0, 0);
        a11 = __builtin_amdgcn_mfma_f32_16x16x32_bf16(vf1, pf1, a11, 0, 0, 0);
      }
    }
    if (c < cmax) WVN(0);                 // own gld16 landed (issued ~300cy ago)
    SB();                                 // reads of this buf done before next
  }                                       // iteration's stage overwrites it

  // epilogue: per-wave l reduction + OH write (no cross-wave combine)
  l0 += __shfl_xor(l0, 16); l0 += __shfl_xor(l0, 32);
  l1 += __shfl_xor(l1, 16); l1 += __shfl_xor(l1, 32);
  const float inv0 = 1.0f / l0, inv1 = 1.0f / l1;
  float* ob0 = OH + (((size_t)(b * SLEN + q0 + qL) * 32) + hh) * 32 + (quad << 2);
  float* ob1 = OH + (((size_t)(b * SLEN + q0 + 16 + qL) * 32) + hh) * 32 + (quad << 2);
  *(float4*)ob0        = (float4){a00[0] * inv0, a00[1] * inv0, a00[2] * inv0, a00[3] * inv0};
  *(float4*)(ob0 + 16) = (float4){a01[0] * inv0, a01[1] * inv0, a01[2] * inv0, a01[3] * inv0};
  *(float4*)ob1        = (float4){a10[0] * inv1, a10[1] * inv1, a10[2] * inv1, a10[3] * inv1};
  *(float4*)(ob1 + 16) = (float4){a11[0] * inv1, a11[1] * inv1, a11[2] * inv1, a11[3] * inv1};
}

// ================= k_tail: fused combine+xfeat + final ======================
// Block = 8 rows. Phase 1 (cxf): wave w reduces rows 2w,2w+1 -> XA/XS1 in LDS.
// Phase 2 (final): out[8][1024] = XA·A1T + XS1·A2T, A1T/A2T hoisted per-f.
__global__ void __launch_bounds__(256) k_tail(const float* __restrict__ OH,
    const float* __restrict__ dl, const float* __restrict__ FS,
    const float* __restrict__ FD, const float* __restrict__ A1T,
    const float* __restrict__ A2T, float* __restrict__ out) {
  __shared__ float XAs[8][16];
  __shared__ float XS1s[8][16];
  const int t = threadIdx.x;
  const int w = t >> 6, lane = t & 63;
  const int rbase = blockIdx.x * 8;           // 512 blocks
  {
    const float lam0 = dl[lane >> 3];
    const float lam1 = dl[8 + (lane >> 3)];
    const float* oh0 = OH + (size_t)(rbase + w * 2) * 1024;
    float4 y1a0 = *(const float4*)(oh0 + lane * 4);
    float4 y1b0 = *(const float4*)(oh0 + 256 + lane * 4);
    float4 y2a0 = *(const float4*)(oh0 + 512 + lane * 4);
    float4 y2b0 = *(const float4*)(oh0 + 768 + lane * 4);
    float4 y1a1 = *(const float4*)(oh0 + 1024 + lane * 4);
    float4 y1b1 = *(const float4*)(oh0 + 1280 + lane * 4);
    float4 y2a1 = *(const float4*)(oh0 + 1536 + lane * 4);
    float4 y2b1 = *(const float4*)(oh0 + 1792 + lane * 4);
    y2a0.x *= lam0; y2a0.y *= lam0; y2a0.z *= lam0; y2a0.w *= lam0;
    y2b0.x *= lam1; y2b0.y *= lam1; y2b0.z *= lam1; y2b0.w *= lam1;
    y2a1.x *= lam0; y2a1.y *= lam0; y2a1.z *= lam0; y2a1.w *= lam0;
    y2b1.x *= lam1; y2b1.y *= lam1; y2b1.z *= lam1; y2b1.w *= lam1;
    float acc0[16], acc1[16];
    #pragma unroll
    for (int f = 0; f < 16; ++f) {
      float4 sa = *(const float4*)(FS + f * 512 + lane * 4);
      float4 sb = *(const float4*)(FS + f * 512 + 256 + lane * 4);
      float4 da = *(const float4*)(FD + f * 512 + lane * 4);
      float4 db = *(const float4*)(FD + f * 512 + 256 + lane * 4);
      acc0[f] = dot4(y1a0, sa) + dot4(y1b0, sb) + dot4(y2a0, da) + dot4(y2b0, db);
      acc1[f] = dot4(y1a1, sa) + dot4(y1b1, sb) + dot4(y2a1, da) + dot4(y2b1, db);
    }
    #pragma unroll
    for (int f = 0; f < 16; ++f) {
      #pragma unroll
      for (int off = 32; off >= 1; off >>= 1) {
        acc0[f] += __shfl_xor(acc0[f], off);
        acc1[f] += __shfl_xor(acc1[f], off);
      }
    }
    if (lane == 0) {
      #pragma unroll
      for (int f = 0; f < 16; ++f) {
        float xf = acc0[f];
        float xs = 1.0f / (1.0f + expf(-5.0f * xf));
        XAs[w * 2][f] = xf * xs;
        XS1s[w * 2][f] = 1.0f - xs;
        float xg = acc1[f];
        float xt = 1.0f / (1.0f + expf(-5.0f * xg));
        XAs[w * 2 + 1][f] = xg * xt;
        XS1s[w * 2 + 1][f] = 1.0f - xt;
      }
    }
  }
  __syncthreads();
  {
    float4 acc[8];
    #pragma unroll
    for (int rr = 0; rr < 8; ++rr) acc[rr] = (float4){0.f, 0.f, 0.f, 0.f};
    #pragma unroll
    for (int f = 0; f < 16; ++f) {
      float4 a1 = *(const float4*)(A1T + f * 1024 + t * 4);
      float4 a2 = *(const float4*)(A2T + f * 1024 + t * 4);
      #pragma unroll
      for (int rr = 0; rr < 8; ++rr) {
        float xa = XAs[rr][f], x1 = XS1s[rr][f];
        acc[rr].x = fmaf(xa, a1.x, fmaf(x1, a2.x, acc[rr].x));
        acc[rr].y = fmaf(xa, a1.y, fmaf(x1, a2.y, acc[rr].y));
        acc[rr].z = fmaf(xa, a1.z, fmaf(x1, a2.z, acc[rr].z));
        acc[rr].w = fmaf(xa, a1.w, fmaf(x1, a2.w, acc[rr].w));
      }
    }
    #pragma unroll
    for (int rr = 0; rr < 8; ++rr)
      *(float4*)(out + (size_t)(rbase + rr) * 1024 + t * 4) = acc[rr];
  }
}

extern "C" void kernel_launch(void* const* d_in, const int* in_sizes, int n_in,
                              void* d_out, int out_size, void* d_ws, size_t ws_size,
                              hipStream_t stream) {
  const float* x      = (const float*)d_in[0];
  const float* w_qkv  = (const float*)d_in[1];
  const float* feats  = (const float*)d_in[2];
  const float* protos = (const float*)d_in[3];
  const float* theta  = (const float*)d_in[4];
  const float* alpha  = (const float*)d_in[5];
  const float* beta   = (const float*)d_in[6];
  const float* q_gain = (const float*)d_in[7];
  const float* dlam   = (const float*)d_in[8];
  float* out = (float*)d_out;
  float* ws  = (float*)d_ws;

  // workspace layout (QKV intermediate eliminated; ~70MB total)
  float* OH  = ws;                    // 4,194,304
  float* COS = OH  + 4194304;         // 65,536
  float* SIN = COS + 65536;           // 65,536
  float* PT  = SIN + 65536;           // 1,048,576
  float* A1T = PT  + 1048576;         // 16,384
  float* A2T = A1T + 16384;           // 16,384
  unsigned short* QB16 = (unsigned short*)(A2T + 16384);  // 4,194,304
  unsigned short* KB16 = QB16 + 4194304;                  // 4,194,304
  unsigned short* VT16 = KB16 + 4194304;                  // 4,194,304
  unsigned short* Wb   = VT16 + 4194304;                  // 3,145,728
  unsigned short* Xhi  = Wb   + 3145728;                  // 4,194,304
  unsigned short* Xlo  = Xhi  + 4194304;                  // 4,194,304
  float* FS = (float*)(Xlo + 4194304);                    // 8,192
  float* FD = FS + 8192;                                  // 8,192

  k_prep<<<8480, 256, 0, stream>>>(w_qkv, protos, x, feats, Wb, PT,
                                   Xhi, Xlo, COS, SIN, FS, FD);
  k_gemm4<<<256, 512, 0, stream>>>(Xhi, Xlo, Wb, COS, SIN, q_gain,
                                   QB16, KB16, VT16);
  k_mid<<<256, 256, 0, stream>>>(PT, feats, theta, alpha, beta, A1T, A2T);
  k_attn<<<1024, 256, 0, stream>>>(QB16, KB16, VT16, OH);
  k_tail<<<512, 256, 0, stream>>>(OH, dlam, FS, FD, A1T, A2T, out);
}

// Round 10
// 209.707 us; speedup vs baseline: 1.3939x; 1.0469x over previous
//
#include <hip/hip_runtime.h>
#include <hip/hip_bf16.h>
#include <math.h>

// Problem constants
#define DIM   1024
#define NHEAD 16
#define SLEN  2048
#define BATCH 2
#define NROWS (BATCH*SLEN)   // 4096
#define QKV_N 3072

typedef __attribute__((ext_vector_type(8))) short short8v;
typedef __attribute__((ext_vector_type(4))) short short4v;
typedef __attribute__((ext_vector_type(4))) float f32x4;
typedef __attribute__((ext_vector_type(4))) unsigned int u32x4;

// RNE float->bf16 bit tricks (valid for finite, non-overflowing inputs —
// identical result to __float2bfloat16 / jnp astype for our value ranges)
__device__ __forceinline__ unsigned short rne16(float f) {
  unsigned u = __float_as_uint(f);
  u += 0x7FFFu + ((u >> 16) & 1u);
  return (unsigned short)(u >> 16);
}
__device__ __forceinline__ float rnef(float f) {
  unsigned u = __float_as_uint(f);
  u += 0x7FFFu + ((u >> 16) & 1u);
  return __uint_as_float(u & 0xFFFF0000u);
}
// pack two floats as bf16 pair (RNE), low = a, high = b.
// v_cvt_pk_bf16_f32 is RNE on gfx950 -> bit-identical to the bit-trick pk2.
__device__ __forceinline__ unsigned pk2(float a, float b) {
  unsigned r;
  asm("v_cvt_pk_bf16_f32 %0, %1, %2" : "=v"(r) : "v"(a), "v"(b));
  return r;
}

// async global->LDS, 16 bytes per lane; LDS dest = wave-uniform base + lane*16
__device__ __forceinline__ void gld16(const unsigned short* g, unsigned short* l) {
  __builtin_amdgcn_global_load_lds(
      (const __attribute__((address_space(1))) unsigned int*)g,
      (__attribute__((address_space(3))) unsigned int*)l, 16, 0, 0);
}

__device__ __forceinline__ float dot4(float4 a, float4 b) {
  return fmaf(a.x, b.x, fmaf(a.y, b.y, fmaf(a.z, b.z, a.w * b.w)));
}

// ================= k_prep: all independent input transforms =================
// blocks [0,3072)      ternary(w_qkv) -> bf16 Wb      (float4/lane)
// blocks [3072,4096)   ternary(protos) -> fp32 PT     (float4/lane)
// blocks [4096,8192)   xsplit (x -> Xhi,Xlo)
// blocks [8192,8448)   rope tables
// blocks [8448,8480)   feature split FS/FD
// Ternary reduction tree is a BIT-EXACT replica of the old 64-lane tree:
// old lane = 4*j + e (j = lane-group index, e = elem); old offsets {32,16,8,4}
// == per-component shfl offsets {8,4,2,1}; old offsets {2,1} == final
// (a0+a2)+(a1+a3). Same values, same association order -> same scale bits.
__global__ void __launch_bounds__(256) k_prep(
    const float* __restrict__ w_qkv, const float* __restrict__ protos,
    const float* __restrict__ x, const float* __restrict__ F,
    unsigned short* __restrict__ Wb, float* __restrict__ PT,
    unsigned short* __restrict__ Xhi, unsigned short* __restrict__ Xlo,
    float* __restrict__ cosT, float* __restrict__ sinT,
    float* __restrict__ FS, float* __restrict__ FD) {
  const int blk = blockIdx.x, tid = threadIdx.x;
  if (blk < 4096) {                        // ternary (w_qkv or protos)
    const bool isw = (blk < 3072);
    const int idx = (isw ? blk * 256 + tid : (blk - 3072) * 256 + tid) * 4;
    const float* src = isw ? w_qkv : protos;
    float4 v = *(const float4*)(src + idx);
    float b0 = rnef(v.x), b1 = rnef(v.y), b2 = rnef(v.z), b3 = rnef(v.w);
    float a0 = fabsf(b0), a1 = fabsf(b1), a2 = fabsf(b2), a3 = fabsf(b3);
    #pragma unroll
    for (int off = 8; off >= 1; off >>= 1) {
      a0 += __shfl_xor(a0, off); a1 += __shfl_xor(a1, off);
      a2 += __shfl_xor(a2, off); a3 += __shfl_xor(a3, off);
    }
    float s = (a0 + a2) + (a1 + a3);
    float scale = fmaxf(rnef(s * (1.0f / 64.0f)), 1e-8f);
    auto tern = [&](float wb) -> float {
      float q = fminf(1.0f, fmaxf(-1.0f, rintf(rnef(wb / scale))));
      float deq = rnef(q * scale);
      float d = rnef(deq - wb);
      return wb + d;
    };
    if (isw) {
      short4v o;
      o[0] = (short)rne16(tern(b0)); o[1] = (short)rne16(tern(b1));
      o[2] = (short)rne16(tern(b2)); o[3] = (short)rne16(tern(b3));
      *(short4v*)(Wb + idx) = o;
    } else {
      float4 o = {rnef(tern(b0)), rnef(tern(b1)), rnef(tern(b2)), rnef(tern(b3))};
      *(float4*)(PT + idx) = o;
    }
  } else if (blk < 8192) {                 // xsplit
    int idx = (blk - 4096) * 256 + tid;
    float4 v = *(const float4*)(x + (size_t)idx * 4);
    short4v hi, lo;
    float h0 = rnef(v.x); hi[0] = (short)rne16(v.x); lo[0] = (short)rne16(v.x - h0);
    float h1 = rnef(v.y); hi[1] = (short)rne16(v.y); lo[1] = (short)rne16(v.y - h1);
    float h2 = rnef(v.z); hi[2] = (short)rne16(v.z); lo[2] = (short)rne16(v.z - h2);
    float h3 = rnef(v.w); hi[3] = (short)rne16(v.w); lo[3] = (short)rne16(v.w - h3);
    *(short4v*)(Xhi + (size_t)idx * 4) = hi;
    *(short4v*)(Xlo + (size_t)idx * 4) = lo;
  } else if (blk < 8448) {                 // rope tables
    int idx = (blk - 8192) * 256 + tid;    // 65536
    int s = idx >> 5, j = idx & 31;
    double inv  = 1.0 / pow(10000.0, (double)(2 * j) / 64.0);
    double ramp = ((double)(2 * j) / 64.0 - 0.25) / 0.75;
    ramp = ramp < 0.0 ? 0.0 : (ramp > 1.0 ? 1.0 : ramp);
    inv /= (ramp * 3.0 + 1.0);
    float freq = (float)s * (float)inv;
    cosT[idx] = (float)cos((double)freq);
    sinT[idx] = (float)sin((double)freq);
  } else {                                 // fsplit
    int idx = (blk - 8448) * 256 + tid;    // 8192
    int f = idx >> 9, hd = idx & 511;
    int h = hd >> 5, d = hd & 31;
    float a = F[f * 1024 + h * 64 + d];
    float b = F[f * 1024 + h * 64 + 32 + d];
    FS[idx] = a + b;
    FD[idx] = b - a;
  }
}

// ===== 256x192 shared-B 4-phase bf16 MFMA GEMM + fused normrope/vtrans ======
// (Xhi+Xlo)·Wb^T over K=1024, tile 256x192; grid 16x16 = 256 blocks.
// K-loop identical to R6/R7 (B staged once per kc, 4 phases, counted vmcnt).
// EPILOGUE: QKV never materialized; rmsnorm/rope/gain + V chunk-permuted
// transpose close within the block (see R8 notes). Bit-exact with R7 outputs.
#define FEN() asm volatile("" ::: "memory")
#define SB()  do { FEN(); __builtin_amdgcn_s_barrier(); FEN(); } while (0)
#define WL()  do { asm volatile("s_waitcnt lgkmcnt(0)" ::: "memory"); \
                   __builtin_amdgcn_sched_barrier(0); } while (0)
#define WVN(n) asm volatile("s_waitcnt vmcnt(" #n ")" ::: "memory")

__global__ void __launch_bounds__(512, 2) k_gemm4(
    const unsigned short* __restrict__ Xhi, const unsigned short* __restrict__ Xlo,
    const unsigned short* __restrict__ Wb,
    const float* __restrict__ cosT, const float* __restrict__ sinT,
    const float* __restrict__ q_gain,
    unsigned short* __restrict__ QB16, unsigned short* __restrict__ KB16,
    unsigned short* __restrict__ VT16) {
  __shared__ unsigned char lds[114688];
  const int t = threadIdx.x;
  const int lane = t & 63;
  const int qL = lane & 15, quad = lane >> 4;
  const int wid = t >> 6;
  const int wm = wid >> 2, wn = wid & 3;   // 2M x 4N waves; per-wave 128x48
  // XCD-aware swizzle: 256 % 8 == 0 -> bijective
  const int bid = blockIdx.x;
  const int swz = (bid & 7) * 32 + (bid >> 3);
  const int by = swz >> 4, bx = swz & 15;
  const int bm = by * 256, bn = bx * 192;
  // swizzled ds_read inner offset (st_16x32 within 1024B subtile)
  const int inner = qL * 64 + ((quad * 16) ^ ((qL & 8) << 2));
  // staging decode: linear dest L -> logical (row, col) via involution P
  int rj[3], cj[3];
  #pragma unroll
  for (int j = 0; j < 3; ++j) {
    int L = j * 8192 + t * 16;
    int Lp = L ^ (((L >> 9) & 1) << 5);
    int st = Lp >> 10;
    rj[j] = (st >> 1) * 16 + ((Lp >> 6) & 15);
    cj[j] = (st & 1) * 32 + ((Lp & 63) >> 1);
  }
  unsigned char* AHI = lds;                 // 2 halves x 16K
  unsigned char* ALO = lds + 32768;         // 2 halves x 16K
  unsigned char* BB  = lds + 65536;         // 2 bufs x 24K

  // stage A half-tile (128 rows interleaved as wm-blocks) of panel at kc
  auto STA = [&](const unsigned short* __restrict__ pan, unsigned char* reg,
                 int kc, int h) {
    unsigned char* lb = reg + h * 16384 + (t >> 6) * 1024;
    #pragma unroll
    for (int j = 0; j < 2; ++j) {
      int rr = bm + ((rj[j] >> 6) * 128) + h * 64 + (rj[j] & 63);
      gld16(pan + (size_t)rr * 1024 + kc + cj[j], (unsigned short*)(lb + j * 8192));
    }
  };
  // stage whole B tile (192 rows) of kc into buf
  auto STB = [&](int kc, int buf) {
    unsigned char* lb = BB + buf * 24576 + (t >> 6) * 1024;
    #pragma unroll
    for (int j = 0; j < 3; ++j)
      gld16(Wb + (size_t)(bn + rj[j]) * 1024 + kc + cj[j],
            (unsigned short*)(lb + j * 8192));
  };

  short8v aF[4][2], bF[3][2];
  f32x4 acc[2][4][3];
  const f32x4 zz = {0.f, 0.f, 0.f, 0.f};
  #pragma unroll
  for (int q_ = 0; q_ < 2; ++q_)
    #pragma unroll
    for (int m_ = 0; m_ < 4; ++m_)
      #pragma unroll
      for (int n_ = 0; n_ < 3; ++n_) acc[q_][m_][n_] = zz;

  auto RA = [&](unsigned char* reg, int qm_) {
    #pragma unroll
    for (int mi = 0; mi < 4; ++mi)
      #pragma unroll
      for (int ks = 0; ks < 2; ++ks)
        aF[mi][ks] = *(const short8v*)(reg + qm_ * 16384 +
                                       ((((wm * 4 + mi) << 1) + ks) << 10) + inner);
  };
  auto RB = [&](int buf) {
    #pragma unroll
    for (int ni = 0; ni < 3; ++ni)
      #pragma unroll
      for (int ks = 0; ks < 2; ++ks)
        bF[ni][ks] = *(const short8v*)(BB + buf * 24576 +
                                       ((((wn * 3 + ni) << 1) + ks) << 10) + inner);
  };
  auto MM = [&](int qm_) {
    __builtin_amdgcn_s_setprio(1);
    #pragma unroll
    for (int ks = 0; ks < 2; ++ks)       // ks outer: dependent pairs 12 apart
      #pragma unroll
      for (int mi = 0; mi < 4; ++mi)
        #pragma unroll
        for (int ni = 0; ni < 3; ++ni)
          acc[qm_][mi][ni] = __builtin_amdgcn_mfma_f32_16x16x32_bf16(
              aF[mi][ks], bF[ni][ks], acc[qm_][mi][ni], 0, 0, 0);
    __builtin_amdgcn_s_setprio(0);
  };

  // prologue: B(0) + Ahi halves + Alo-h0 (9 units); leave newest 4 in flight
  STB(0, 0); STA(Xhi, AHI, 0, 0); STA(Xhi, AHI, 0, 1); STA(Xlo, ALO, 0, 0);
  WVN(4);
  SB();

  #pragma unroll 1
  for (int i = 0; i < 16; ++i) {
    const int kc = i * 64, kn = kc + 64;
    const bool nl = (i < 15);
    const int cb = i & 1, nb = cb ^ 1;
    // ph1: (qm0, hi) — read B once for the whole iteration
    RA(AHI, 0); RB(cb); STA(Xlo, ALO, kc, 1);
    SB(); WL(); MM(0);
    WVN(4);                                   // Ahi-h1(i) landed
    SB();
    // ph2: (qm1, hi)
    RA(AHI, 1);
    if (nl) { STB(kn, nb); STA(Xhi, AHI, kn, 0); }
    SB(); WL(); MM(1);
    if (nl) { WVN(7); } else { WVN(2); }      // Alo-h0(i) landed
    SB();
    // ph3: (qm0, lo)
    RA(ALO, 0);
    if (nl) STA(Xhi, AHI, kn, 1);
    SB(); WL(); MM(0);
    if (nl) { WVN(7); } else { WVN(0); }      // Alo-h1(i) landed
    SB();
    // ph4: (qm1, lo)
    RA(ALO, 1);
    if (nl) STA(Xlo, ALO, kn, 0);
    SB(); WL(); MM(1);
    if (nl) WVN(4);                           // B(i+1), Ahi-h0(i+1) landed
    SB();
  }

  // ===== fused epilogue: per qm half, LDS-stage then normrope/vtrans =====
  float* S = (float*)lds;                  // [128][196] f32
  const int bb = bm >> 11;                 // batch index (256 | 2048)
  const int lg = t & 15;                   // lane within 16-group
  const int g16 = t >> 4;                  // group id 0..31
  const int gch0 = bn >> 6;                // first global 64-col chunk (0..47)

  auto EPI = [&](const f32x4 (&ap)[4][3], int p) {
    // stage this qm-half's acc into S (2-way bank alias = free)
    #pragma unroll
    for (int mi = 0; mi < 4; ++mi)
      #pragma unroll
      for (int ni = 0; ni < 3; ++ni) {
        const int sr = wm * 64 + mi * 16 + quad * 4;
        const int colL = wn * 48 + ni * 16 + qL;
        #pragma unroll
        for (int r = 0; r < 4; ++r)
          S[(sr + r) * 196 + colL] = ap[mi][ni][r];
      }
    SB();
    // q/k chunks: rmsnorm + rope + gain (exact R7 normrope math, bit-exact)
    #pragma unroll 1
    for (int u = g16; u < 384; u += 32) {
      const int chunk = u >> 7, sr = u & 127;
      const int gch = gch0 + chunk;
      if (gch < 32) {
        float4 xv = *(const float4*)&S[sr * 196 + chunk * 64 + lg * 4];
        float s0 = xv.x * xv.x, s1 = xv.y * xv.y;
        float s2 = xv.z * xv.z, s3 = xv.w * xv.w;
        #pragma unroll
        for (int off = 8; off >= 1; off >>= 1) {
          s0 += __shfl_xor(s0, off); s1 += __shfl_xor(s1, off);
          s2 += __shfl_xor(s2, off); s3 += __shfl_xor(s3, off);
        }
        float ss = (s0 + s2) + (s1 + s3);
        float inv = rsqrtf(ss * (1.0f / 64.0f) + 1e-5f);
        float xn0 = xv.x * inv, xn1 = xv.y * inv;
        float xn2 = xv.z * inv, xn3 = xv.w * inv;
        const int s_glob = bm + ((sr >> 6) << 7) + p * 64 + (sr & 63);
        const int srow = s_glob & (SLEN - 1);
        const int j4 = (lg & 7) * 4;
        float4 c4 = *(const float4*)(cosT + srow * 32 + j4);
        float4 n4 = *(const float4*)(sinT + srow * 32 + j4);
        float ot0 = __shfl_xor(xn0, 8), ot1 = __shfl_xor(xn1, 8);
        float ot2 = __shfl_xor(xn2, 8), ot3 = __shfl_xor(xn3, 8);
        const bool hi = (lg & 8) != 0;
        float o0 = hi ? fmaf(xn0, c4.x, -ot0 * n4.x) : fmaf(xn0, c4.x, ot0 * n4.x);
        float o1 = hi ? fmaf(xn1, c4.y, -ot1 * n4.y) : fmaf(xn1, c4.y, ot1 * n4.y);
        float o2 = hi ? fmaf(xn2, c4.z, -ot2 * n4.z) : fmaf(xn2, c4.z, ot2 * n4.z);
        float o3 = hi ? fmaf(xn3, c4.w, -ot3 * n4.w) : fmaf(xn3, c4.w, ot3 * n4.w);
        const int h = gch & 15;
        const int hh = h + (hi ? 16 : 0);
        size_t addr = (((size_t)(bb * 32 + hh) * SLEN) + srow) * 32 + j4;
        short4v o;
        if (gch < 16) {
          const float FOLD = 0.17677669529663687f * 1.4426950408889634f;
          float gq = q_gain[h];
          o[0] = (short)rne16(o0 * gq * FOLD); o[1] = (short)rne16(o1 * gq * FOLD);
          o[2] = (short)rne16(o2 * gq * FOLD); o[3] = (short)rne16(o3 * gq * FOLD);
          *(short4v*)(QB16 + addr) = o;
        } else {
          o[0] = (short)rne16(o0); o[1] = (short)rne16(o1);
          o[2] = (short)rne16(o2); o[3] = (short)rne16(o3);
          *(short4v*)(KB16 + addr) = o;
        }
      }
    }
    // v chunks: chunk-permuted transpose store (same layout as R7 vtrans)
    const int wid8 = t >> 6;
    const int cl = t & 63;
    #pragma unroll 1
    for (int c3 = 0; c3 < 3; ++c3) {
      const int gch = gch0 + c3;
      if (gch >= 32) {
        const int hv = gch - 32;
        const int hh = (cl >= 32) ? hv + 16 : hv;
        const int dpl = cl & 31;
        unsigned short* vrow = VT16 + (((size_t)(bb * 32 + hh) * 32) + dpl) * SLEN;
        #pragma unroll
        for (int k4 = 0; k4 < 4; ++k4) {
          const int sr = wid8 * 16 + k4 * 4;
          const int s_glob = bm + ((sr >> 6) << 7) + p * 64 + (sr & 63);
          const int srow = s_glob & (SLEN - 1);
          const int c32 = srow & ~31, kc = srow & 31;
          const int p0 = 8 * ((kc & 15) >> 2) + 4 * (kc >> 4);
          short4v o;
          o[0] = (short)rne16(S[(sr + 0) * 196 + c3 * 64 + cl]);
          o[1] = (short)rne16(S[(sr + 1) * 196 + c3 * 64 + cl]);
          o[2] = (short)rne16(S[(sr + 2) * 196 + c3 * 64 + cl]);
          o[3] = (short)rne16(S[(sr + 3) * 196 + c3 * 64 + cl]);
          *(short4v*)(vrow + c32 + p0) = o;
        }
      }
    }
    SB();                                  // reads done before next stage
  };
  EPI(acc[0], 0);                          // literal acc index (rule #20)
  EPI(acc[1], 1);
}

// ====== MFMA flash attention (+ protproj rider blocks, R8 k_mid verbatim) ===
// blocks [0,1024): attention — EXACT R8 single-chunk-staged loop (known good).
// blocks [1024,1280): protproj — byte-identical body of R8's k_mid (reads PT
// produced by k_prep), with o = (bk-1024)*4 + wave. Single variable vs R8:
// the dispatch merge. If this round fails, the merge mechanism is the bug;
// if it passes, R9's fault lay in pair-staging and/or inline ternary.
__global__ void __launch_bounds__(256, 6) k_attn(
    const unsigned short* __restrict__ QB16,
    const unsigned short* __restrict__ KB16,
    const unsigned short* __restrict__ VT16,
    float* __restrict__ OH,
    const float* __restrict__ PT, const float* __restrict__ F,
    const float* __restrict__ thp, const float* __restrict__ alp,
    const float* __restrict__ bep,
    float* __restrict__ A1T, float* __restrict__ A2T) {
  __shared__ unsigned char kv[2][4096];   // [buf][Kt0 1K | Kt1 1K | Vh0 1K | Vh1 1K]
  const int bk = blockIdx.x;              // 1280
  if (bk >= 1024) {                       // ---- protproj rider (R8 k_mid) ----
    const int t = threadIdx.x;
    const int w = t >> 6, lane = t & 63;
    const int o = (bk - 1024) * 4 + w;
    const float* pr = PT + (size_t)o * 1024;
    float4 p0 = *(const float4*)(pr + lane * 4);
    float4 p1 = *(const float4*)(pr + 256 + lane * 4);
    float4 p2 = *(const float4*)(pr + 512 + lane * 4);
    float4 p3 = *(const float4*)(pr + 768 + lane * 4);
    float acc[16];
    #pragma unroll
    for (int f = 0; f < 16; ++f) {
      const float* fr = F + (size_t)f * 1024;
      float4 f0 = *(const float4*)(fr + lane * 4);
      float4 f1 = *(const float4*)(fr + 256 + lane * 4);
      float4 f2 = *(const float4*)(fr + 512 + lane * 4);
      float4 f3 = *(const float4*)(fr + 768 + lane * 4);
      acc[f] = dot4(p0, f0) + dot4(p1, f1) + dot4(p2, f2) + dot4(p3, f3);
    }
    #pragma unroll
    for (int f = 0; f < 16; ++f) {
      #pragma unroll
      for (int off = 32; off >= 1; off >>= 1) acc[f] += __shfl_xor(acc[f], off);
    }
    if (lane == 0) {
      float th = fabsf(*thp), al = fabsf(*alp), be = fabsf(*bep);
      #pragma unroll
      for (int f = 0; f < 16; ++f) {
        float pf = acc[f];
        float ps = 1.0f / (1.0f + expf(-5.0f * pf));
        float pa = pf * ps;
        A1T[f * 1024 + o] = th * pa - al * (1.0f - ps);
        A2T[f * 1024 + o] = -be * pa;
      }
    }
    return;
  }
  // ---- attention (R8 verbatim) ----
  const int wid = threadIdx.x >> 6;
  const int lane = threadIdx.x & 63;
  const int qL = lane & 15, quad = lane >> 4;
  const int combo = bk & 63;              // XCD-local K/V (combo%8 == bk%8)
  // G sequence {15,14,13,12, 0,1,2,3, 11,10,9,8, 4,5,6,7}: windows of 4
  // spaced 4 apart sum to 30 each -> per-CU chunk totals equalized.
  const int ii = bk >> 6, qd = ii >> 2, rr = ii & 3;
  const int G = (qd & 1) ? (rr + ((qd & 2) << 1)) : (15 - rr - ((qd & 2) << 1));
  const int qbw = 4 * G + wid;            // this wave's q-block
  const int cmax = 4 * G + 3;             // chunks staged per block
  const int b = combo >> 5, hh = combo & 31;
  const int q0 = qbw * 32;

  const unsigned short* QB = QB16 + (size_t)(b * 32 + hh) * SLEN * 32;
  const unsigned short* KB = KB16 + (size_t)(b * 32 + hh) * SLEN * 32;
  const unsigned short* VT = VT16 + (size_t)(b * 32 + hh) * 32 * SLEN;

  const short8v qf0 = *(const short8v*)(QB + (size_t)(q0 + qL) * 32 + quad * 8);
  const short8v qf1 = *(const short8v*)(QB + (size_t)(q0 + 16 + qL) * 32 + quad * 8);
  const f32x4 zz = {0.f, 0.f, 0.f, 0.f};
  f32x4 a00 = zz, a01 = zz, a10 = zz, a11 = zz;
  float l0 = 0.f, l1 = 0.f;

  // staging duty: w0 -> K tile0 (keys 32c+qL), w1 -> K tile1 (keys 32c+16+qL),
  // w2 -> V h0 (d=qL), w3 -> V h1 (d=16+qL). Lane's 16B source == exactly the
  // fragment reader lane (qL,quad) consumes -> LDS read is linear lane*16.
  const unsigned short* sbase = (wid < 2)
      ? KB + (size_t)(wid * 16 + qL) * 32 + quad * 8
      : VT + (size_t)((wid - 2) * 16 + qL) * 2048 + quad * 8;
  const int sstep = (wid < 2) ? 1024 : 32;  // shorts per chunk along source
  unsigned short* d0 = (unsigned short*)(&kv[0][0] + wid * 1024);
  unsigned short* d1 = (unsigned short*)(&kv[1][0] + wid * 1024);

  gld16(sbase, d0);                       // stage chunk 0 -> buf 0
  WVN(0);
  SB();

  #pragma unroll 1
  for (int c = 0; c <= cmax; ++c) {
    const unsigned char* kb = &kv[c & 1][0];
    if (c < cmax) gld16(sbase + (size_t)(c + 1) * sstep, (c & 1) ? d0 : d1);
    if (c <= qbw) {
      short8v kf0 = *(const short8v*)(kb + lane * 16);
      short8v kf1 = *(const short8v*)(kb + 1024 + lane * 16);
      short8v vf0 = *(const short8v*)(kb + 2048 + lane * 16);
      short8v vf1 = *(const short8v*)(kb + 3072 + lane * 16);
      if (c < qbw) {                      // full (unmasked) chunk
        f32x4 s00 = __builtin_amdgcn_mfma_f32_16x16x32_bf16(kf0, qf0, zz, 0, 0, 0);
        f32x4 s01 = __builtin_amdgcn_mfma_f32_16x16x32_bf16(kf1, qf0, zz, 0, 0, 0);
        f32x4 s10 = __builtin_amdgcn_mfma_f32_16x16x32_bf16(kf0, qf1, zz, 0, 0, 0);
        f32x4 s11 = __builtin_amdgcn_mfma_f32_16x16x32_bf16(kf1, qf1, zz, 0, 0, 0);
        float p00[4], p01[4], p10[4], p11[4];
        #pragma unroll
        for (int r = 0; r < 4; ++r) {
          p00[r] = __builtin_amdgcn_exp2f(s00[r]);
          p01[r] = __builtin_amdgcn_exp2f(s01[r]);
          p10[r] = __builtin_amdgcn_exp2f(s10[r]);
          p11[r] = __builtin_amdgcn_exp2f(s11[r]);
        }
        l0 += (p00[0] + p00[1] + p00[2] + p00[3]) + (p01[0] + p01[1] + p01[2] + p01[3]);
        l1 += (p10[0] + p10[1] + p10[2] + p10[3]) + (p11[0] + p11[1] + p11[2] + p11[3]);
        u32x4 up0 = {pk2(p00[0], p00[1]), pk2(p00[2], p00[3]),
                     pk2(p01[0], p01[1]), pk2(p01[2], p01[3])};
        u32x4 up1 = {pk2(p10[0], p10[1]), pk2(p10[2], p10[3]),
                     pk2(p11[0], p11[1]), pk2(p11[2], p11[3])};
        short8v pf0 = __builtin_bit_cast(short8v, up0);
        short8v pf1 = __builtin_bit_cast(short8v, up1);
        a00 = __builtin_amdgcn_mfma_f32_16x16x32_bf16(vf0, pf0, a00, 0, 0, 0);
        a01 = __builtin_amdgcn_mfma_f32_16x16x32_bf16(vf1, pf0, a01, 0, 0, 0);
        a10 = __builtin_amdgcn_mfma_f32_16x16x32_bf16(vf0, pf1, a10, 0, 0, 0);
        a11 = __builtin_amdgcn_mfma_f32_16x16x32_bf16(vf1, pf1, a11, 0, 0, 0);
      } else {                            // tail chunk (diagonal masks)
        f32x4 s00 = __builtin_amdgcn_mfma_f32_16x16x32_bf16(kf0, qf0, zz, 0, 0, 0);
        f32x4 s10 = __builtin_amdgcn_mfma_f32_16x16x32_bf16(kf0, qf1, zz, 0, 0, 0);
        f32x4 s11 = __builtin_amdgcn_mfma_f32_16x16x32_bf16(kf1, qf1, zz, 0, 0, 0);
        float p00[4], p10[4], p11[4];
        #pragma unroll
        for (int r = 0; r < 4; ++r) {
          bool v = (4 * quad + r) <= qL;  // same predicate for s00 and s11
          p00[r] = v ? __builtin_amdgcn_exp2f(s00[r]) : 0.f;
          p10[r] = __builtin_amdgcn_exp2f(s10[r]);   // always valid
          p11[r] = v ? __builtin_amdgcn_exp2f(s11[r]) : 0.f;
        }
        l0 += (p00[0] + p00[1] + p00[2] + p00[3]);
        l1 += (p10[0] + p10[1] + p10[2] + p10[3]) + (p11[0] + p11[1] + p11[2] + p11[3]);
        u32x4 up0 = {pk2(p00[0], p00[1]), pk2(p00[2], p00[3]), 0u, 0u};
        u32x4 up1 = {pk2(p10[0], p10[1]), pk2(p10[2], p10[3]),
                     pk2(p11[0], p11[1]), pk2(p11[2], p11[3])};
        short8v pf0 = __builtin_bit_cast(short8v, up0);
        short8v pf1 = __builtin_bit_cast(short8v, up1);
        a00 = __builtin_amdgcn_mfma_f32_16x16x32_bf16(vf0, pf0, a00, 0, 0, 0);
        a01 = __builtin_amdgcn_mfma_f32_16x16x32_bf16(vf1, pf0, a01, 0, 0, 0);
        a10 = __builtin_amdgcn_mfma_f32_16x16x32_bf16(vf0, pf1, a10, 0, 0, 0);
        a11 = __builtin_amdgcn_mfma_f32_16x16x32_bf16(vf1, pf1, a11, 0, 0, 0);
      }
    }
    if (c < cmax) WVN(0);                 // own gld16 landed (issued ~300cy ago)
    SB();                                 // reads of this buf done before next
  }                                       // iteration's stage overwrites it

  // epilogue: per-wave l reduction + OH write (no cross-wave combine)
  l0 += __shfl_xor(l0, 16); l0 += __shfl_xor(l0, 32);
  l1 += __shfl_xor(l1, 16); l1 += __shfl_xor(l1, 32);
  const float inv0 = 1.0f / l0, inv1 = 1.0f / l1;
  float* ob0 = OH + (((size_t)(b * SLEN + q0 + qL) * 32) + hh) * 32 + (quad << 2);
  float* ob1 = OH + (((size_t)(b * SLEN + q0 + 16 + qL) * 32) + hh) * 32 + (quad << 2);
  *(float4*)ob0        = (float4){a00[0] * inv0, a00[1] * inv0, a00[2] * inv0, a00[3] * inv0};
  *(float4*)(ob0 + 16) = (float4){a01[0] * inv0, a01[1] * inv0, a01[2] * inv0, a01[3] * inv0};
  *(float4*)ob1        = (float4){a10[0] * inv1, a10[1] * inv1, a10[2] * inv1, a10[3] * inv1};
  *(float4*)(ob1 + 16) = (float4){a11[0] * inv1, a11[1] * inv1, a11[2] * inv1, a11[3] * inv1};
}

// ================= k_tail: fused combine+xfeat + final ======================
// Block = 8 rows. Phase 1 (cxf): wave w reduces rows 2w,2w+1 -> XA/XS1 in LDS.
// Phase 2 (final): out[8][1024] = XA·A1T + XS1·A2T, A1T/A2T hoisted per-f.
__global__ void __launch_bounds__(256) k_tail(const float* __restrict__ OH,
    const float* __restrict__ dl, const float* __restrict__ FS,
    const float* __restrict__ FD, const float* __restrict__ A1T,
    const float* __restrict__ A2T, float* __restrict__ out) {
  __shared__ float XAs[8][16];
  __shared__ float XS1s[8][16];
  const int t = threadIdx.x;
  const int w = t >> 6, lane = t & 63;
  const int rbase = blockIdx.x * 8;           // 512 blocks
  {
    const float lam0 = dl[lane >> 3];
    const float lam1 = dl[8 + (lane >> 3)];
    const float* oh0 = OH + (size_t)(rbase + w * 2) * 1024;
    float4 y1a0 = *(const float4*)(oh0 + lane * 4);
    float4 y1b0 = *(const float4*)(oh0 + 256 + lane * 4);
    float4 y2a0 = *(const float4*)(oh0 + 512 + lane * 4);
    float4 y2b0 = *(const float4*)(oh0 + 768 + lane * 4);
    float4 y1a1 = *(const float4*)(oh0 + 1024 + lane * 4);
    float4 y1b1 = *(const float4*)(oh0 + 1280 + lane * 4);
    float4 y2a1 = *(const float4*)(oh0 + 1536 + lane * 4);
    float4 y2b1 = *(const float4*)(oh0 + 1792 + lane * 4);
    y2a0.x *= lam0; y2a0.y *= lam0; y2a0.z *= lam0; y2a0.w *= lam0;
    y2b0.x *= lam1; y2b0.y *= lam1; y2b0.z *= lam1; y2b0.w *= lam1;
    y2a1.x *= lam0; y2a1.y *= lam0; y2a1.z *= lam0; y2a1.w *= lam0;
    y2b1.x *= lam1; y2b1.y *= lam1; y2b1.z *= lam1; y2b1.w *= lam1;
    float acc0[16], acc1[16];
    #pragma unroll
    for (int f = 0; f < 16; ++f) {
      float4 sa = *(const float4*)(FS + f * 512 + lane * 4);
      float4 sb = *(const float4*)(FS + f * 512 + 256 + lane * 4);
      float4 da = *(const float4*)(FD + f * 512 + lane * 4);
      float4 db = *(const float4*)(FD + f * 512 + 256 + lane * 4);
      acc0[f] = dot4(y1a0, sa) + dot4(y1b0, sb) + dot4(y2a0, da) + dot4(y2b0, db);
      acc1[f] = dot4(y1a1, sa) + dot4(y1b1, sb) + dot4(y2a1, da) + dot4(y2b1, db);
    }
    #pragma unroll
    for (int f = 0; f < 16; ++f) {
      #pragma unroll
      for (int off = 32; off >= 1; off >>= 1) {
        acc0[f] += __shfl_xor(acc0[f], off);
        acc1[f] += __shfl_xor(acc1[f], off);
      }
    }
    if (lane == 0) {
      #pragma unroll
      for (int f = 0; f < 16; ++f) {
        float xf = acc0[f];
        float xs = 1.0f / (1.0f + expf(-5.0f * xf));
        XAs[w * 2][f] = xf * xs;
        XS1s[w * 2][f] = 1.0f - xs;
        float xg = acc1[f];
        float xt = 1.0f / (1.0f + expf(-5.0f * xg));
        XAs[w * 2 + 1][f] = xg * xt;
        XS1s[w * 2 + 1][f] = 1.0f - xt;
      }
    }
  }
  __syncthreads();
  {
    float4 acc[8];
    #pragma unroll
    for (int rr = 0; rr < 8; ++rr) acc[rr] = (float4){0.f, 0.f, 0.f, 0.f};
    #pragma unroll
    for (int f = 0; f < 16; ++f) {
      float4 a1 = *(const float4*)(A1T + f * 1024 + t * 4);
      float4 a2 = *(const float4*)(A2T + f * 1024 + t * 4);
      #pragma unroll
      for (int rr = 0; rr < 8; ++rr) {
        float xa = XAs[rr][f], x1 = XS1s[rr][f];
        acc[rr].x = fmaf(xa, a1.x, fmaf(x1, a2.x, acc[rr].x));
        acc[rr].y = fmaf(xa, a1.y, fmaf(x1, a2.y, acc[rr].y));
        acc[rr].z = fmaf(xa, a1.z, fmaf(x1, a2.z, acc[rr].z));
        acc[rr].w = fmaf(xa, a1.w, fmaf(x1, a2.w, acc[rr].w));
      }
    }
    #pragma unroll
    for (int rr = 0; rr < 8; ++rr)
      *(float4*)(out + (size_t)(rbase + rr) * 1024 + t * 4) = acc[rr];
  }
}

extern "C" void kernel_launch(void* const* d_in, const int* in_sizes, int n_in,
                              void* d_out, int out_size, void* d_ws, size_t ws_size,
                              hipStream_t stream) {
  const float* x      = (const float*)d_in[0];
  const float* w_qkv  = (const float*)d_in[1];
  const float* feats  = (const float*)d_in[2];
  const float* protos = (const float*)d_in[3];
  const float* theta  = (const float*)d_in[4];
  const float* alpha  = (const float*)d_in[5];
  const float* beta   = (const float*)d_in[6];
  const float* q_gain = (const float*)d_in[7];
  const float* dlam   = (const float*)d_in[8];
  float* out = (float*)d_out;
  float* ws  = (float*)d_ws;

  // workspace layout (QKV intermediate eliminated; ~70MB total)
  float* OH  = ws;                    // 4,194,304
  float* COS = OH  + 4194304;         // 65,536
  float* SIN = COS + 65536;           // 65,536
  float* PT  = SIN + 65536;           // 1,048,576
  float* A1T = PT  + 1048576;         // 16,384
  float* A2T = A1T + 16384;           // 16,384
  unsigned short* QB16 = (unsigned short*)(A2T + 16384);  // 4,194,304
  unsigned short* KB16 = QB16 + 4194304;                  // 4,194,304
  unsigned short* VT16 = KB16 + 4194304;                  // 4,194,304
  unsigned short* Wb   = VT16 + 4194304;                  // 3,145,728
  unsigned short* Xhi  = Wb   + 3145728;                  // 4,194,304
  unsigned short* Xlo  = Xhi  + 4194304;                  // 4,194,304
  float* FS = (float*)(Xlo + 4194304);                    // 8,192
  float* FD = FS + 8192;                                  // 8,192

  k_prep<<<8480, 256, 0, stream>>>(w_qkv, protos, x, feats, Wb, PT,
                                   Xhi, Xlo, COS, SIN, FS, FD);
  k_gemm4<<<256, 512, 0, stream>>>(Xhi, Xlo, Wb, COS, SIN, q_gain,
                                   QB16, KB16, VT16);
  k_attn<<<1280, 256, 0, stream>>>(QB16, KB16, VT16, OH, PT, feats,
                                   theta, alpha, beta, A1T, A2T);
  k_tail<<<512, 256, 0, stream>>>(OH, dlam, FS, FD, A1T, A2T, out);
}